// Round 6
// baseline (1619.881 us; speedup 1.0000x reference)
//
#include <hip/hip_runtime.h>

// Problem constants (shapes fixed by reference setup_inputs)
#define NS   64
#define DDIM 512
#define CDIM 512
#define TDIM 1024
#define CB   64     // c-rows per workgroup
#define TBLK 128    // t-tile per outer iteration (== w)
#define BK   64     // k(d)-chunk staged per inner iteration
#define SCALE 0.04419417382415922f   // 512^-0.5

typedef __attribute__((ext_vector_type(4)))  float f32x4;
typedef __attribute__((ext_vector_type(16))) float f32x16;
typedef __attribute__((ext_vector_type(4)))  short s16x4;
typedef __attribute__((ext_vector_type(8)))  short s16x8;

// Barrier that orders LDS only — does NOT drain vmcnt, so global prefetches
// stay in flight across it.
#define LGKM_BARRIER() asm volatile("s_waitcnt lgkmcnt(0)\n\ts_barrier" ::: "memory")

// fp32 -> bf16 bits, round-to-nearest-even
__device__ __forceinline__ unsigned short f2bf(float f) {
  unsigned int b = __float_as_uint(f);
  return (unsigned short)((b + 0x7FFFu + ((b >> 16) & 1u)) >> 16);
}
__device__ __forceinline__ float bf2f(unsigned short u) {
  return __uint_as_float(((unsigned int)u) << 16);
}

// 16B async global->LDS (DMA; LDS dest = wave-uniform base + lane*16)
__device__ __forceinline__ void gload_lds16(const void* g, void* l) {
  __builtin_amdgcn_global_load_lds(
      (const __attribute__((address_space(1))) unsigned int*)g,
      (__attribute__((address_space(3))) unsigned int*)l, 16, 0, 0);
}

// ===========================================================================
// FUSED PRE-PASS (unchanged from Round-5 verified run): one kernel, 3 jobs.
// ===========================================================================
__global__ __launch_bounds__(256)
void prep_kernel(const float* __restrict__ query,
                 const float* __restrict__ key,
                 const float* __restrict__ value,
                 unsigned short* __restrict__ Qt,
                 unsigned short* __restrict__ Kt,
                 unsigned short* __restrict__ Vb)
{
  __shared__ float tile[64 * 65];
  const int b   = blockIdx.x;
  const int tid = threadIdx.x;

  if (b < 12288) {
    // ---- transpose-convert job ----
    const float* src; unsigned short* dst; int C, n, rb, cb;
    if (b < 4096) {              // Q: grid 8(cb) x 8(rb) x 64(n)
      const int local = b;
      C = CDIM; cb = (local & 7) * 64; rb = ((local >> 3) & 7) * 64;
      n = local >> 6; src = query; dst = Qt;
    } else {                     // K: grid 16(cb) x 8(rb) x 64(n)
      const int local = b - 4096;
      C = TDIM; cb = (local & 15) * 64; rb = ((local >> 4) & 7) * 64;
      n = local >> 7; src = key; dst = Kt;
    }
    const float* s = src + (size_t)n * 512 * C + (size_t)rb * C + cb;
    #pragma unroll
    for (int i = 0; i < 4; ++i) {
      const int idx = i * 256 + tid;
      const int r   = idx >> 4;               // 0..63 (d within tile)
      const int c4  = (idx & 15) << 2;        // 0,4..60 (c within tile)
      f32x4 v = *(const f32x4*)(s + (size_t)r * C + c4);
      tile[(c4 + 0) * 65 + r] = v[0];
      tile[(c4 + 1) * 65 + r] = v[1];
      tile[(c4 + 2) * 65 + r] = v[2];
      tile[(c4 + 3) * 65 + r] = v[3];
    }
    __syncthreads();
    unsigned short* d = dst + (size_t)n * 512 * C + (size_t)cb * 512 + rb;
    #pragma unroll
    for (int i = 0; i < 2; ++i) {
      const int idx = i * 256 + tid;
      const int c   = idx >> 3;               // 0..63
      const int r8  = (idx & 7) << 3;         // 0,8..56
      s16x8 o;
      #pragma unroll
      for (int j = 0; j < 8; ++j) o[j] = (short)f2bf(tile[c * 65 + r8 + j]);
      *(s16x8*)(d + (size_t)c * 512 + r8) = o;
    }
  } else {
    // ---- V convert job: 2048 blocks x 16384 elems, fully coalesced ----
    const int vb = b - 12288;
    const size_t base = (size_t)vb * 16384;
    #pragma unroll
    for (int i = 0; i < 8; ++i) {
      const size_t off = base + (size_t)i * 2048 + (size_t)tid * 8;
      f32x4 v0 = *(const f32x4*)(value + off);
      f32x4 v1 = *(const f32x4*)(value + off + 4);
      s16x8 o;
      o[0] = (short)f2bf(v0[0]); o[1] = (short)f2bf(v0[1]);
      o[2] = (short)f2bf(v0[2]); o[3] = (short)f2bf(v0[3]);
      o[4] = (short)f2bf(v1[0]); o[5] = (short)f2bf(v1[1]);
      o[6] = (short)f2bf(v1[2]); o[7] = (short)f2bf(v1[3]);
      *(s16x8*)(Vb + off) = o;
    }
  }
}

// ---------------------------------------------------------------------------
// Main fused kernel — R6 change: LDS 66.5 KB -> 48.5 KB (Ps aliased into the
// BS1 half-buffer, which is dead during phases 2-3: kit7 consumes BS1 and
// kit0's prefetch targets BS0) => 3 blocks/CU instead of 2 (24 waves/CU).
// Ps stride 132 -> 128 shorts with XOR swizzle (idx = c*128 + (t ^ ((c&15)<<3)))
// so stride-256B rows stay 2-way-conflict-free on the PV column-slice reads.
// New lgkm-barrier at tb-end orders phase-3 Ps reads before next-tb's DMA
// into the aliased region.
// LDS layout (bytes):
//   As0 @ 0      [64][128B]  bf16 Q-tile (XOR-swizzled content, linear layout)
//   As1 @ 8192
//   Bs0 @ 16384  [128][128B] bf16 K-tile
//   Bs1 @ 32768  (aliased by Ps [64][128] bf16 swizzled during phases 2-3)
//   Zacc@ 49152  [64] f32 ; invZ @ 49408 [64] f32
//   Obuf@ 0      [64][129] f32 (epilogue, overlaps As/Bs after full drain)
// ---------------------------------------------------------------------------
#define AS0_OFF 0
#define AS1_OFF 8192
#define BS0_OFF 16384
#define BS1_OFF 32768
#define PS_OFF  32768          // alias of BS1
#define ZA_OFF  49152
#define IZ_OFF  49408
#define SMEM_BYTES 49664

// Stage chunk g (k0 = (g&7)*64, t0 = (g>>3)*128): As 1 issue + Bs 2 issues,
// 16B/lane. Source address carries the XOR swizzle (byte ^= (row&7)<<4) so
// LDS stays linear (global_load_lds requirement) and the swizzled
// ds_read_b128 on the consume side is bank-conflict-spread (rule #21: the
// source permutation and the read permutation are the same involution).
__device__ __forceinline__ void issue_tiles(const char* __restrict__ Qn,
                                            const char* __restrict__ Kn,
                                            char* as_lds, char* bs_lds,
                                            int g, int tid) {
  if (g > 63) g = 63;                       // clamped re-issue (harmless dup)
  const int k0b = (g & 7) * (BK * 2);
  const int t0  = (g >> 3) * TBLK;
  {
    const int row  = tid >> 3;              // c row 0..63
    const int colb = ((tid & 7) << 4) ^ ((row & 7) << 4);
    gload_lds16(Qn + (size_t)row * (DDIM * 2) + k0b + colb, as_lds + tid * 16);
  }
  #pragma unroll
  for (int i = 0; i < 2; ++i) {
    const int idx  = i * 512 + tid;
    const int row  = idx >> 3;              // t row 0..127
    const int colb = ((idx & 7) << 4) ^ ((row & 7) << 4);
    gload_lds16(Kn + (size_t)(t0 + row) * (DDIM * 2) + k0b + colb, bs_lds + idx * 16);
  }
}

__global__ __launch_bounds__(512, 6)   // 3 blocks/CU (LDS 48.5 KB), VGPR<=85
void attn_main(const unsigned short* __restrict__ Qt,   // [n][c][d] bf16
               const unsigned short* __restrict__ Kt,   // [n][t][d] bf16
               const unsigned short* __restrict__ Vb,   // [n][d][t] bf16
               const float* __restrict__ ratios,
               float* __restrict__ out)
{
  __shared__ __align__(16) char smem[SMEM_BYTES];
  unsigned short* Ps = (unsigned short*)(smem + PS_OFF);
  float* Zacc = (float*)(smem + ZA_OFF);
  float* invZ = (float*)(smem + IZ_OFF);
  float* Obuf = (float*)smem;

  // XCD swizzle: all 8 c-blocks of one sample -> same XCD (same L2)
  const int lin = blockIdx.x + (int)gridDim.x * blockIdx.y;  // 0..511
  const int n   = 8 * (lin & 7) + (lin >> 6);
  const int c0  = ((lin >> 3) & 7) * CB;

  const int tid  = threadIdx.x;
  const int wave = tid >> 6;
  const int lane = tid & 63;
  const int l31  = lane & 31;
  const int lhi  = lane >> 5;

  float r = ratios[n];
  int vw = (int)floorf(128.0f * r + 0.5f);
  if (vw > 128) vw = 128;

  const char* Qn = (const char*)(Qt + (size_t)n * CDIM * DDIM + (size_t)c0 * DDIM);
  const char* Kn = (const char*)(Kt + (size_t)n * TDIM * DDIM);
  const unsigned short* Vn = Vb + (size_t)n * DDIM * TDIM;

  f32x16 o_acc[2][2];
  #pragma unroll
  for (int a = 0; a < 2; ++a)
    #pragma unroll
    for (int b = 0; b < 2; ++b)
      #pragma unroll
      for (int i = 0; i < 16; ++i) o_acc[a][b][i] = 0.0f;

  const int p1_ct = wave & 1;   // c strip (2 x 32)
  const int p1_tt = wave >> 1;  // t strip (4 x 32)

  if (tid < 64) Zacc[tid] = 0.0f;
  issue_tiles(Qn, Kn, smem + AS0_OFF, smem + BS0_OFF, 0, tid);
  // order Zacc init; do NOT drain vmcnt (prefetch stays in flight)
  LGKM_BARRIER();

  const int swz = (l31 & 7) << 4;
  const int aro = (32 * p1_ct + l31) * 128;
  const int bro = (32 * p1_tt + l31) * 128;

  for (int tb = 0; tb < 8; ++tb) {
    const int t0 = tb * TBLK;
    f32x16 s_acc;
    #pragma unroll
    for (int i = 0; i < 16; ++i) s_acc[i] = 0.0f;

    // ---- phase 1: S(64x128) += Q^T K over d; DMA-staged, dbuf, vmcnt(3) ----
    #pragma unroll
    for (int kit = 0; kit < 8; ++kit) {
      const int g = tb * 8 + kit;           // (g&1) == (kit&1) since 8|tb*8
      char* asb = smem + ((kit & 1) ? AS1_OFF : AS0_OFF);
      char* bsb = smem + ((kit & 1) ? BS1_OFF : BS0_OFF);
      char* asn = smem + ((kit & 1) ? AS0_OFF : AS1_OFF);
      char* bsn = smem + ((kit & 1) ? BS0_OFF : BS1_OFF);
      // prefetch next chunk into the buffer every wave finished reading last kit
      issue_tiles(Qn, Kn, asn, bsn, g + 1, tid);
      // wait for CURRENT chunk's 3 loads only (3 newer stay in flight)
      asm volatile("s_waitcnt vmcnt(3)\n\ts_barrier" ::: "memory");
      __builtin_amdgcn_s_setprio(1);       // T5: favor MFMA-entering waves
      #pragma unroll
      for (int ks = 0; ks < 4; ++ks) {
        const int coff = (ks * 32 + 16 * lhi) ^ swz;
        s16x8 av = *(const s16x8*)(asb + aro + coff);
        s16x8 bv = *(const s16x8*)(bsb + bro + coff);
        s_acc = __builtin_amdgcn_mfma_f32_32x32x16_bf16(av, bv, s_acc, 0, 0, 0);
      }
      __builtin_amdgcn_s_setprio(0);
      // drain frag reads so next kit may overwrite this buffer (no vmcnt drain)
      LGKM_BARRIER();
    }
    // NOTE: after kit7, BS1/AS1 hold consumed data; the in-flight prefetch
    // (next tb's kit0) targets AS0/BS0 — so Ps (alias of BS1) is safe below.

    // ---- phase 2: p = mask * exp(s*scale) ----
    {
      const int tcol = 32 * p1_tt + l31;
      const float pm = (tcol < vw) ? 1.0f : 0.0f;
      #pragma unroll
      for (int rg = 0; rg < 16; ++rg) {
        const int c_loc = 32 * p1_ct + (rg & 3) + 8 * (rg >> 2) + 4 * lhi;
        float p = pm * __expf(s_acc[rg] * SCALE);
        Ps[c_loc * 128 + (tcol ^ ((c_loc & 15) << 3))] = f2bf(p);
      }
    }
    LGKM_BARRIER();

    // ---- Z row-sum accumulation (vectorized b64 reads, swizzled) ----
    {
      const int zr = tid >> 3;
      const int zo = (tid & 7) * 16;
      const int zswz = (zr & 15) << 3;
      float zs = 0.0f;
      #pragma unroll
      for (int j4 = 0; j4 < 4; ++j4) {
        s16x4 v4 = *(const s16x4*)&Ps[zr * 128 + ((zo + 4 * j4) ^ zswz)];
        zs += bf2f((unsigned short)v4[0]) + bf2f((unsigned short)v4[1])
            + bf2f((unsigned short)v4[2]) + bf2f((unsigned short)v4[3]);
      }
      zs += __shfl_xor(zs, 1);
      zs += __shfl_xor(zs, 2);
      zs += __shfl_xor(zs, 4);
      if ((tid & 7) == 0) Zacc[zr] += zs;
    }

    // ---- phase 3: O += P * V^T ; V direct bf16 from global, dist-2 prefetch ----
    {
      const unsigned short* vr0 = Vn + (size_t)(64 * wave + l31) * TDIM + t0;
      const unsigned short* vr1 = vr0 + (size_t)32 * TDIM;
      s16x8 va[2], vb2[2];
      va[0]  = *(const s16x8*)(vr0 + 8 * lhi);
      vb2[0] = *(const s16x8*)(vr1 + 8 * lhi);
      va[1]  = *(const s16x8*)(vr0 + 16 + 8 * lhi);
      vb2[1] = *(const s16x8*)(vr1 + 16 + 8 * lhi);
      const int prow0 = (32 * 0 + l31);
      const int prow1 = (32 * 1 + l31);
      const int psw0 = (prow0 & 15) << 3;
      const int psw1 = (prow1 & 15) << 3;
      #pragma unroll
      for (int ks = 0; ks < 8; ++ks) {
        const int kk = ks * 16 + 8 * lhi;
        s16x8 pa[2];
        {
          s16x4 x0 = *(const s16x4*)&Ps[prow0 * 128 + (kk ^ psw0)];
          s16x4 x1 = *(const s16x4*)&Ps[prow0 * 128 + ((kk + 4) ^ psw0)];
          pa[0] = __builtin_shufflevector(x0, x1, 0, 1, 2, 3, 4, 5, 6, 7);
          s16x4 y0 = *(const s16x4*)&Ps[prow1 * 128 + (kk ^ psw1)];
          s16x4 y1 = *(const s16x4*)&Ps[prow1 * 128 + ((kk + 4) ^ psw1)];
          pa[1] = __builtin_shufflevector(y0, y1, 0, 1, 2, 3, 4, 5, 6, 7);
        }
        s16x8 b0 = va[ks & 1];
        s16x8 b1 = vb2[ks & 1];
        if (ks < 6) {
          va[ks & 1]  = *(const s16x8*)(vr0 + (ks + 2) * 16 + 8 * lhi);
          vb2[ks & 1] = *(const s16x8*)(vr1 + (ks + 2) * 16 + 8 * lhi);
        }
        __builtin_amdgcn_s_setprio(1);     // T5: MFMA quad
        o_acc[0][0] = __builtin_amdgcn_mfma_f32_32x32x16_bf16(pa[0], b0, o_acc[0][0], 0, 0, 0);
        o_acc[1][0] = __builtin_amdgcn_mfma_f32_32x32x16_bf16(pa[1], b0, o_acc[1][0], 0, 0, 0);
        o_acc[0][1] = __builtin_amdgcn_mfma_f32_32x32x16_bf16(pa[0], b1, o_acc[0][1], 0, 0, 0);
        o_acc[1][1] = __builtin_amdgcn_mfma_f32_32x32x16_bf16(pa[1], b1, o_acc[1][1], 0, 0, 0);
        __builtin_amdgcn_s_setprio(0);
      }
    }

    // tb-end barrier: all waves' phase-3 Ps reads done before next tb's
    // kit0 issues DMA into AS1/BS1 (= Ps alias). lgkm-only: the in-flight
    // kit0 prefetch (vmem) is NOT drained.
    LGKM_BARRIER();
  }

  // ---- epilogue: drain the clamped trailing prefetch, then normalize+store ----
  asm volatile("s_waitcnt vmcnt(0) lgkmcnt(0)\n\ts_barrier" ::: "memory");
  if (tid < 64) invZ[tid] = 1.0f / Zacc[tid];
  LGKM_BARRIER();

  float* outn = out + (size_t)n * DDIM * CDIM + c0;
  for (int ch = 0; ch < 4; ++ch) {          // d-chunk of 128
    if ((wave >> 1) == ch) {
      const int s = wave & 1;
      #pragma unroll
      for (int ci = 0; ci < 2; ++ci)
        #pragma unroll
        for (int dt = 0; dt < 2; ++dt)
          #pragma unroll
          for (int rg = 0; rg < 16; ++rg) {
            const int c_loc = 32 * ci + (rg & 3) + 8 * (rg >> 2) + 4 * lhi;
            const int ddl = 64 * s + 32 * dt + l31;
            Obuf[c_loc * 129 + ddl] = o_acc[ci][dt][rg] * invZ[c_loc];
          }
    }
    LGKM_BARRIER();
    {
      const int c  = tid & 63;
      const int db = tid >> 6;
      #pragma unroll
      for (int p = 0; p < 16; ++p) {
        const int ddl = db + 8 * p;
        outn[(size_t)(128 * ch + ddl) * CDIM + c] = Obuf[c * 129 + ddl];
      }
    }
    LGKM_BARRIER();
  }
}

// ===========================================================================
// FALLBACK PATH — previous session's harness-verified kernel (545.3 µs),
// used only if ws_size is too small for the workspace path.
// ===========================================================================
#define FB_AS_OFF 0
#define FB_BS_OFF 8704
#define FB_PS_OFF 26112
#define FB_ZA_OFF 43008
#define FB_IZ_OFF 43264
#define FB_SMEM_BYTES 43520

struct QKRegs { f32x4 q0, q1, ka0, ka1, kb0, kb1; };
struct VRegs  { f32x4 a0, a1, b0, b1; };

__device__ __forceinline__ void issue_qk(QKRegs& r,
                                         const float* __restrict__ qbase,
                                         const float* __restrict__ kbase,
                                         int k0, int t0,
                                         int a_mg, int a_kq, int b_tg, int b_kq) {
  const float* gq = qbase + (size_t)(k0 + 2 * a_kq) * CDIM + 4 * a_mg;
  r.q0 = *(const f32x4*)gq;
  r.q1 = *(const f32x4*)(gq + CDIM);
  const float* gk0 = kbase + (size_t)(k0 + 2 * b_kq) * TDIM + t0 + 4 * b_tg;
  const float* gk1 = gk0 + (size_t)32 * TDIM;
  r.ka0 = *(const f32x4*)gk0;
  r.ka1 = *(const f32x4*)(gk0 + TDIM);
  r.kb0 = *(const f32x4*)gk1;
  r.kb1 = *(const f32x4*)(gk1 + TDIM);
}

__device__ __forceinline__ void issue_v(VRegs& r,
                                        const float* __restrict__ vrow0,
                                        int ks, int lhi) {
  const int kk = ks * 16 + 8 * lhi;
  const float* vp0 = vrow0 + kk;
  r.a0 = *(const f32x4*)vp0;
  r.a1 = *(const f32x4*)(vp0 + 4);
  const float* vp1 = vp0 + (size_t)32 * TDIM;
  r.b0 = *(const f32x4*)vp1;
  r.b1 = *(const f32x4*)(vp1 + 4);
}

__device__ __forceinline__ s16x8 cvt_bv(const f32x4& x0, const f32x4& x1) {
  s16x8 bv;
  bv[0] = (short)f2bf(x0[0]); bv[1] = (short)f2bf(x0[1]);
  bv[2] = (short)f2bf(x0[2]); bv[3] = (short)f2bf(x0[3]);
  bv[4] = (short)f2bf(x1[0]); bv[5] = (short)f2bf(x1[1]);
  bv[6] = (short)f2bf(x1[2]); bv[7] = (short)f2bf(x1[3]);
  return bv;
}

__global__ __launch_bounds__(512, 1)
void attn_fused_fallback(const float* __restrict__ query,
                         const float* __restrict__ key,
                         const float* __restrict__ value,
                         const float* __restrict__ ratios,
                         float* __restrict__ out)
{
  __shared__ __align__(16) char smem[FB_SMEM_BYTES];
  unsigned short* As = (unsigned short*)(smem + FB_AS_OFF);
  unsigned short* Bs = (unsigned short*)(smem + FB_BS_OFF);
  unsigned short* Ps = (unsigned short*)(smem + FB_PS_OFF);
  float* Zacc = (float*)(smem + FB_ZA_OFF);
  float* invZ = (float*)(smem + FB_IZ_OFF);
  float* Obuf = (float*)(smem + FB_AS_OFF);

  const int lin  = blockIdx.x + (int)gridDim.x * blockIdx.y;  // 0..511
  const int n    = 8 * (lin & 7) + (lin >> 6);
  const int c0   = ((lin >> 3) & 7) * CB;

  const int tid  = threadIdx.x;
  const int wave = tid >> 6;
  const int lane = tid & 63;
  const int l31  = lane & 31;
  const int lhi  = lane >> 5;

  float r = ratios[n];
  int vw = (int)floorf(128.0f * r + 0.5f);
  if (vw > 128) vw = 128;

  if (tid < 64) Zacc[tid] = 0.0f;

  const float* qbase = query + (size_t)n * DDIM * CDIM + c0;
  const float* kbase = key   + (size_t)n * DDIM * TDIM;
  const float* vbase = value + (size_t)n * DDIM * TDIM;

  f32x16 o_acc[2][2];
  #pragma unroll
  for (int a = 0; a < 2; ++a)
    #pragma unroll
    for (int b = 0; b < 2; ++b)
      #pragma unroll
      for (int i = 0; i < 16; ++i) o_acc[a][b][i] = 0.0f;

  const int p1_ct = wave & 1;
  const int p1_tt = wave >> 1;
  const int a_mg = tid & 15, a_kq = tid >> 4;
  const int b_tg = tid & 31, b_kq = tid >> 5;
  const float* vrow0_base = vbase + (size_t)(64 * wave + l31) * TDIM;

  QKRegs buf[2];
  issue_qk(buf[0], qbase, kbase, 0,  0, a_mg, a_kq, b_tg, b_kq);
  issue_qk(buf[1], qbase, kbase, BK, 0, a_mg, a_kq, b_tg, b_kq);

  LGKM_BARRIER();

  for (int tb = 0; tb < 8; ++tb) {
    const int t0 = tb * TBLK;
    f32x16 s_acc;
    #pragma unroll
    for (int i = 0; i < 16; ++i) s_acc[i] = 0.0f;

    #pragma unroll
    for (int kit = 0; kit < 8; ++kit) {
      const int g = tb * 8 + kit;
      QKRegs& rb = buf[kit & 1];

      LGKM_BARRIER();

      #pragma unroll
      for (int j = 0; j < 4; ++j) {
        unsigned int pk = (unsigned int)f2bf(rb.q0[j]) | ((unsigned int)f2bf(rb.q1[j]) << 16);
        *(unsigned int*)&As[(4 * a_mg + j) * 68 + 2 * a_kq] = pk;
      }
      #pragma unroll
      for (int j = 0; j < 4; ++j) {
        unsigned int p0 = (unsigned int)f2bf(rb.ka0[j]) | ((unsigned int)f2bf(rb.ka1[j]) << 16);
        unsigned int p1 = (unsigned int)f2bf(rb.kb0[j]) | ((unsigned int)f2bf(rb.kb1[j]) << 16);
        *(unsigned int*)&Bs[(4 * b_tg + j) * 68 + 2 * b_kq]      = p0;
        *(unsigned int*)&Bs[(4 * b_tg + j) * 68 + 2 * b_kq + 32] = p1;
      }

      {
        int gg = g + 2; if (gg > 63) gg = 63;
        issue_qk(rb, qbase, kbase, (gg & 7) * BK, (gg >> 3) * TBLK,
                 a_mg, a_kq, b_tg, b_kq);
      }

      LGKM_BARRIER();

      const int arow = (32 * p1_ct + l31) * 68;
      const int brow = (32 * p1_tt + l31) * 68;
      #pragma unroll
      for (int ks = 0; ks < 4; ++ks) {
        const int koff = ks * 16 + 8 * lhi;
        s16x4 a0 = *(const s16x4*)&As[arow + koff];
        s16x4 a1 = *(const s16x4*)&As[arow + koff + 4];
        s16x4 b0 = *(const s16x4*)&Bs[brow + koff];
        s16x4 b1 = *(const s16x4*)&Bs[brow + koff + 4];
        s16x8 av = __builtin_shufflevector(a0, a1, 0, 1, 2, 3, 4, 5, 6, 7);
        s16x8 bv = __builtin_shufflevector(b0, b1, 0, 1, 2, 3, 4, 5, 6, 7);
        s_acc = __builtin_amdgcn_mfma_f32_32x32x16_bf16(av, bv, s_acc, 0, 0, 0);
      }
    }

    {
      const int tcol = 32 * p1_tt + l31;
      const float pm = (tcol < vw) ? 1.0f : 0.0f;
      #pragma unroll
      for (int rg = 0; rg < 16; ++rg) {
        const int c_loc = 32 * p1_ct + (rg & 3) + 8 * (rg >> 2) + 4 * lhi;
        float p = pm * __expf(s_acc[rg] * SCALE);
        Ps[c_loc * 132 + tcol] = f2bf(p);
      }
    }
    LGKM_BARRIER();

    {
      const int zr = tid >> 3;
      const int zo = (tid & 7) * 16;
      float zs = 0.0f;
      #pragma unroll
      for (int j = 0; j < 16; ++j) zs += bf2f(Ps[zr * 132 + zo + j]);
      zs += __shfl_xor(zs, 1);
      zs += __shfl_xor(zs, 2);
      zs += __shfl_xor(zs, 4);
      if ((tid & 7) == 0) Zacc[zr] += zs;
    }

    {
      const float* vrow0 = vrow0_base + t0;
      VRegs vb[2];
      issue_v(vb[0], vrow0, 0, lhi);
      issue_v(vb[1], vrow0, 1, lhi);
      #pragma unroll
      for (int ks = 0; ks < 8; ++ks) {
        const int kk = ks * 16 + 8 * lhi;
        s16x8 pa[2];
        #pragma unroll
        for (int ci = 0; ci < 2; ++ci) {
          const int row = (32 * ci + l31) * 132;
          s16x4 x0 = *(const s16x4*)&Ps[row + kk];
          s16x4 x1 = *(const s16x4*)&Ps[row + kk + 4];
          pa[ci] = __builtin_shufflevector(x0, x1, 0, 1, 2, 3, 4, 5, 6, 7);
        }
        VRegs& vr = vb[ks & 1];
        s16x8 bv0 = cvt_bv(vr.a0, vr.a1);
        s16x8 bv1 = cvt_bv(vr.b0, vr.b1);
        if (ks < 6) issue_v(vr, vrow0, ks + 2, lhi);
        o_acc[0][0] = __builtin_amdgcn_mfma_f32_32x32x16_bf16(pa[0], bv0, o_acc[0][0], 0, 0, 0);
        o_acc[1][0] = __builtin_amdgcn_mfma_f32_32x32x16_bf16(pa[1], bv0, o_acc[1][0], 0, 0, 0);
        o_acc[0][1] = __builtin_amdgcn_mfma_f32_32x32x16_bf16(pa[0], bv1, o_acc[0][1], 0, 0, 0);
        o_acc[1][1] = __builtin_amdgcn_mfma_f32_32x32x16_bf16(pa[1], bv1, o_acc[1][1], 0, 0, 0);
      }
    }
  }

  LGKM_BARRIER();
  if (tid < 64) invZ[tid] = 1.0f / Zacc[tid];
  LGKM_BARRIER();

  float* outn = out + (size_t)n * DDIM * CDIM + c0;
  for (int ch = 0; ch < 4; ++ch) {
    if ((wave >> 1) == ch) {
      const int s = wave & 1;
      #pragma unroll
      for (int ci = 0; ci < 2; ++ci)
        #pragma unroll
        for (int dt = 0; dt < 2; ++dt)
          #pragma unroll
          for (int rg = 0; rg < 16; ++rg) {
            const int c_loc = 32 * ci + (rg & 3) + 8 * (rg >> 2) + 4 * lhi;
            const int ddl = 64 * s + 32 * dt + l31;
            Obuf[c_loc * 129 + ddl] = o_acc[ci][dt][rg] * invZ[c_loc];
          }
    }
    LGKM_BARRIER();
    {
      const int c = tid & 63;
      const int db = tid >> 6;
      #pragma unroll
      for (int p = 0; p < 16; ++p) {
        const int ddl = db + 8 * p;
        outn[(size_t)(128 * ch + ddl) * CDIM + c] = Obuf[c * 129 + ddl];
      }
    }
    LGKM_BARRIER();
  }
}

extern "C" void kernel_launch(void* const* d_in, const int* in_sizes, int n_in,
                              void* d_out, int out_size, void* d_ws, size_t ws_size,
                              hipStream_t stream) {
  const float* query  = (const float*)d_in[0];
  const float* key    = (const float*)d_in[1];
  const float* value  = (const float*)d_in[2];
  const float* ratios = (const float*)d_in[3];
  float* out = (float*)d_out;
  (void)in_sizes; (void)n_in; (void)out_size;

  // workspace: Qt (32 MB) | Kt (64 MB) | Vb (64 MB)  => 160 MB bf16 total
  const size_t needQ = (size_t)NS * CDIM * DDIM;       // shorts
  const size_t needK = (size_t)NS * TDIM * DDIM;       // shorts
  const size_t needV = (size_t)NS * DDIM * TDIM;       // shorts
  const size_t need_bytes = (needQ + needK + needV) * sizeof(unsigned short);

  if (d_ws != nullptr && ws_size >= need_bytes) {
    unsigned short* Qt = (unsigned short*)d_ws;
    unsigned short* Kt = Qt + needQ;
    unsigned short* Vb = Kt + needK;
    prep_kernel<<<dim3(14336), 256, 0, stream>>>(query, key, value, Qt, Kt, Vb);
    attn_main<<<dim3(CDIM / CB, NS), 512, 0, stream>>>(Qt, Kt, Vb, ratios, out);
  } else {
    attn_fused_fallback<<<dim3(CDIM / CB, NS), 512, 0, stream>>>(query, key, value, ratios, out);
  }
}

// Round 7
// 585.533 us; speedup vs baseline: 2.7665x; 2.7665x over previous
//
#include <hip/hip_runtime.h>

// Problem constants (shapes fixed by reference setup_inputs)
#define NS   64
#define DDIM 512
#define CDIM 512
#define TDIM 1024
#define CB   64     // c-rows per workgroup
#define TBLK 128    // t-tile per outer iteration (== w)
#define BK   64     // k(d)-chunk staged per inner iteration
#define SCALE 0.04419417382415922f   // 512^-0.5

typedef __attribute__((ext_vector_type(4)))  float f32x4;
typedef __attribute__((ext_vector_type(16))) float f32x16;
typedef __attribute__((ext_vector_type(4)))  short s16x4;
typedef __attribute__((ext_vector_type(8)))  short s16x8;

// Barrier that orders LDS only — does NOT drain vmcnt, so global prefetches
// stay in flight across it.
#define LGKM_BARRIER() asm volatile("s_waitcnt lgkmcnt(0)\n\ts_barrier" ::: "memory")

// fp32 -> bf16 bits, round-to-nearest-even
__device__ __forceinline__ unsigned short f2bf(float f) {
  unsigned int b = __float_as_uint(f);
  return (unsigned short)((b + 0x7FFFu + ((b >> 16) & 1u)) >> 16);
}
__device__ __forceinline__ float bf2f(unsigned short u) {
  return __uint_as_float(((unsigned int)u) << 16);
}

// 16B async global->LDS (DMA; LDS dest = wave-uniform base + lane*16)
__device__ __forceinline__ void gload_lds16(const void* g, void* l) {
  __builtin_amdgcn_global_load_lds(
      (const __attribute__((address_space(1))) unsigned int*)g,
      (__attribute__((address_space(3))) unsigned int*)l, 16, 0, 0);
}

// ===========================================================================
// FUSED PRE-PASS (unchanged from Round-5 verified run): one kernel, 3 jobs.
// ===========================================================================
__global__ __launch_bounds__(256)
void prep_kernel(const float* __restrict__ query,
                 const float* __restrict__ key,
                 const float* __restrict__ value,
                 unsigned short* __restrict__ Qt,
                 unsigned short* __restrict__ Kt,
                 unsigned short* __restrict__ Vb)
{
  __shared__ float tile[64 * 65];
  const int b   = blockIdx.x;
  const int tid = threadIdx.x;

  if (b < 12288) {
    // ---- transpose-convert job ----
    const float* src; unsigned short* dst; int C, n, rb, cb;
    if (b < 4096) {              // Q: grid 8(cb) x 8(rb) x 64(n)
      const int local = b;
      C = CDIM; cb = (local & 7) * 64; rb = ((local >> 3) & 7) * 64;
      n = local >> 6; src = query; dst = Qt;
    } else {                     // K: grid 16(cb) x 8(rb) x 64(n)
      const int local = b - 4096;
      C = TDIM; cb = (local & 15) * 64; rb = ((local >> 4) & 7) * 64;
      n = local >> 7; src = key; dst = Kt;
    }
    const float* s = src + (size_t)n * 512 * C + (size_t)rb * C + cb;
    #pragma unroll
    for (int i = 0; i < 4; ++i) {
      const int idx = i * 256 + tid;
      const int r   = idx >> 4;               // 0..63 (d within tile)
      const int c4  = (idx & 15) << 2;        // 0,4..60 (c within tile)
      f32x4 v = *(const f32x4*)(s + (size_t)r * C + c4);
      tile[(c4 + 0) * 65 + r] = v[0];
      tile[(c4 + 1) * 65 + r] = v[1];
      tile[(c4 + 2) * 65 + r] = v[2];
      tile[(c4 + 3) * 65 + r] = v[3];
    }
    __syncthreads();
    unsigned short* d = dst + (size_t)n * 512 * C + (size_t)cb * 512 + rb;
    #pragma unroll
    for (int i = 0; i < 2; ++i) {
      const int idx = i * 256 + tid;
      const int c   = idx >> 3;               // 0..63
      const int r8  = (idx & 7) << 3;         // 0,8..56
      s16x8 o;
      #pragma unroll
      for (int j = 0; j < 8; ++j) o[j] = (short)f2bf(tile[c * 65 + r8 + j]);
      *(s16x8*)(d + (size_t)c * 512 + r8) = o;
    }
  } else {
    // ---- V convert job: 2048 blocks x 16384 elems, fully coalesced ----
    const int vb = b - 12288;
    const size_t base = (size_t)vb * 16384;
    #pragma unroll
    for (int i = 0; i < 8; ++i) {
      const size_t off = base + (size_t)i * 2048 + (size_t)tid * 8;
      f32x4 v0 = *(const f32x4*)(value + off);
      f32x4 v1 = *(const f32x4*)(value + off + 4);
      s16x8 o;
      o[0] = (short)f2bf(v0[0]); o[1] = (short)f2bf(v0[1]);
      o[2] = (short)f2bf(v0[2]); o[3] = (short)f2bf(v0[3]);
      o[4] = (short)f2bf(v1[0]); o[5] = (short)f2bf(v1[1]);
      o[6] = (short)f2bf(v1[2]); o[7] = (short)f2bf(v1[3]);
      *(s16x8*)(Vb + off) = o;
    }
  }
}

// ---------------------------------------------------------------------------
// Main fused kernel — R7:
//  * REVERT launch_bounds to (512,4). R6's (512,6) capped unified VGPR+AGPR
//    at ~85 < the kernel's ~128 (o_acc 64 AGPR + ~64 VGPR) -> accumulator
//    spill to scratch (VGPR_Count 40, WRITE_SIZE 3 GB). Reg file, not LDS,
//    binds occupancy at 2 blocks/CU for this structure.
//  * Tri-buffer depth-2 staging pipeline: at kit g, compute chunk g (loads
//    issued 2 kits ago, ~600cy cover), prefetch chunk g+2. Wait is
//    vmcnt(6) = 2 chunks x 3 loads in flight. LDS 72.5 KB still fits
//    2 blocks/CU (the true cap), so the 3rd buffer is free.
//  * Ps (16 KB) aliases the just-consumed buffer's Bs region (rotates:
//    fb = (cur+2)%3). Swizzled layout [64][128] shorts, idx = c*128 ^
//    ((c&15)<<3) — verified correct in R6 (passed).
// LDS layout (bytes): buf k at k*24576 (As 8 KB @ +0, Bs 16 KB @ +8192);
//   Zacc @ 73728, invZ @ 73984; Obuf [64][129] f32 @ 0 (epilogue, after drain).
// ---------------------------------------------------------------------------
#define BUFSZ   24576
#define ZA_OFF  73728
#define IZ_OFF  73984
#define SMEM_BYTES 74240

// Stage chunk g (k0 = (g&7)*64, t0 = (g>>3)*128): As 1 issue + Bs 2 issues,
// 16B/lane. Source address carries the XOR swizzle (byte ^= (row&7)<<4) so
// LDS stays linear (global_load_lds requirement) and the swizzled
// ds_read_b128 on the consume side is bank-conflict-spread (rule #21: the
// source permutation and the read permutation are the same involution).
__device__ __forceinline__ void issue_tiles(const char* __restrict__ Qn,
                                            const char* __restrict__ Kn,
                                            char* as_lds, char* bs_lds,
                                            int g, int tid) {
  if (g > 63) g = 63;                       // clamped re-issue (harmless dup)
  const int k0b = (g & 7) * (BK * 2);
  const int t0  = (g >> 3) * TBLK;
  {
    const int row  = tid >> 3;              // c row 0..63
    const int colb = ((tid & 7) << 4) ^ ((row & 7) << 4);
    gload_lds16(Qn + (size_t)row * (DDIM * 2) + k0b + colb, as_lds + tid * 16);
  }
  #pragma unroll
  for (int i = 0; i < 2; ++i) {
    const int idx  = i * 512 + tid;
    const int row  = idx >> 3;              // t row 0..127
    const int colb = ((idx & 7) << 4) ^ ((row & 7) << 4);
    gload_lds16(Kn + (size_t)(t0 + row) * (DDIM * 2) + k0b + colb, bs_lds + idx * 16);
  }
}

__global__ __launch_bounds__(512, 4)   // 2 blocks/CU; full 128-reg budget
void attn_main(const unsigned short* __restrict__ Qt,   // [n][c][d] bf16
               const unsigned short* __restrict__ Kt,   // [n][t][d] bf16
               const unsigned short* __restrict__ Vb,   // [n][d][t] bf16
               const float* __restrict__ ratios,
               float* __restrict__ out)
{
  __shared__ __align__(16) char smem[SMEM_BYTES];
  float* Zacc = (float*)(smem + ZA_OFF);
  float* invZ = (float*)(smem + IZ_OFF);
  float* Obuf = (float*)smem;

  // XCD swizzle: all 8 c-blocks of one sample -> same XCD (same L2)
  const int lin = blockIdx.x + (int)gridDim.x * blockIdx.y;  // 0..511
  const int n   = 8 * (lin & 7) + (lin >> 6);
  const int c0  = ((lin >> 3) & 7) * CB;

  const int tid  = threadIdx.x;
  const int wave = tid >> 6;
  const int lane = tid & 63;
  const int l31  = lane & 31;
  const int lhi  = lane >> 5;

  float r = ratios[n];
  int vw = (int)floorf(128.0f * r + 0.5f);
  if (vw > 128) vw = 128;

  const char* Qn = (const char*)(Qt + (size_t)n * CDIM * DDIM + (size_t)c0 * DDIM);
  const char* Kn = (const char*)(Kt + (size_t)n * TDIM * DDIM);
  const unsigned short* Vn = Vb + (size_t)n * DDIM * TDIM;

  f32x16 o_acc[2][2];
  #pragma unroll
  for (int a = 0; a < 2; ++a)
    #pragma unroll
    for (int b = 0; b < 2; ++b)
      #pragma unroll
      for (int i = 0; i < 16; ++i) o_acc[a][b][i] = 0.0f;

  const int p1_ct = wave & 1;   // c strip (2 x 32)
  const int p1_tt = wave >> 1;  // t strip (4 x 32)

  if (tid < 64) Zacc[tid] = 0.0f;
  // prologue: chunk0 -> buf0, chunk1 -> buf1
  issue_tiles(Qn, Kn, smem, smem + 8192, 0, tid);
  issue_tiles(Qn, Kn, smem + BUFSZ, smem + BUFSZ + 8192, 1, tid);
  // order Zacc init; do NOT drain vmcnt (prefetches stay in flight)
  LGKM_BARRIER();

  const int swz = (l31 & 7) << 4;
  const int aro = (32 * p1_ct + l31) * 128;
  const int bro = (32 * p1_tt + l31) * 128;

  int cur = 0;   // buffer index (wave-uniform, SGPR) of the chunk computed this kit

  for (int tb = 0; tb < 8; ++tb) {
    const int t0 = tb * TBLK;
    f32x16 s_acc;
    #pragma unroll
    for (int i = 0; i < 16; ++i) s_acc[i] = 0.0f;

    // ---- phase 1: S(64x128) += Q^T K over d; tri-buffer, depth-2, vmcnt(6) ----
    #pragma unroll
    for (int kit = 0; kit < 8; ++kit) {
      const int g = tb * 8 + kit;
      int nxt = cur + 2; if (nxt >= 3) nxt -= 3;
      char* curb = smem + cur * BUFSZ;
      char* nxtb = smem + nxt * BUFSZ;
      // prefetch chunk g+2 into the buffer consumed at kit-1 (lgkm-drained)
      issue_tiles(Qn, Kn, nxtb, nxtb + 8192, g + 2, tid);
      // wait for chunk g's 3 loads only; 6 newer (g+1, g+2) stay in flight
      asm volatile("s_waitcnt vmcnt(6)\n\ts_barrier" ::: "memory");
      __builtin_amdgcn_s_setprio(1);       // T5: favor MFMA-entering waves
      #pragma unroll
      for (int ks = 0; ks < 4; ++ks) {
        const int coff = (ks * 32 + 16 * lhi) ^ swz;
        s16x8 av = *(const s16x8*)(curb + aro + coff);
        s16x8 bv = *(const s16x8*)(curb + 8192 + bro + coff);
        s_acc = __builtin_amdgcn_mfma_f32_32x32x16_bf16(av, bv, s_acc, 0, 0, 0);
      }
      __builtin_amdgcn_s_setprio(0);
      // drain frag reads so the next kit's prefetch may overwrite this buffer
      LGKM_BARRIER();
      cur = cur + 1; if (cur >= 3) cur -= 3;
    }

    // free buffer = the one consumed at kit7 (in-flight prefetches target the
    // other two); its Bs region hosts Ps for phases 2-3.
    int fb = cur + 2; if (fb >= 3) fb -= 3;
    unsigned short* Ps = (unsigned short*)(smem + fb * BUFSZ + 8192);

    // ---- phase 2: p = mask * exp(s*scale) ----
    {
      const int tcol = 32 * p1_tt + l31;
      const float pm = (tcol < vw) ? 1.0f : 0.0f;
      #pragma unroll
      for (int rg = 0; rg < 16; ++rg) {
        const int c_loc = 32 * p1_ct + (rg & 3) + 8 * (rg >> 2) + 4 * lhi;
        float p = pm * __expf(s_acc[rg] * SCALE);
        Ps[c_loc * 128 + (tcol ^ ((c_loc & 15) << 3))] = f2bf(p);
      }
    }
    LGKM_BARRIER();

    // ---- Z row-sum accumulation (vectorized b64 reads, swizzled) ----
    {
      const int zr = tid >> 3;
      const int zo = (tid & 7) * 16;
      const int zswz = (zr & 15) << 3;
      float zs = 0.0f;
      #pragma unroll
      for (int j4 = 0; j4 < 4; ++j4) {
        s16x4 v4 = *(const s16x4*)&Ps[zr * 128 + ((zo + 4 * j4) ^ zswz)];
        zs += bf2f((unsigned short)v4[0]) + bf2f((unsigned short)v4[1])
            + bf2f((unsigned short)v4[2]) + bf2f((unsigned short)v4[3]);
      }
      zs += __shfl_xor(zs, 1);
      zs += __shfl_xor(zs, 2);
      zs += __shfl_xor(zs, 4);
      if ((tid & 7) == 0) Zacc[zr] += zs;
    }

    // ---- phase 3: O += P * V^T ; V direct bf16 from global, dist-2 prefetch ----
    {
      const unsigned short* vr0 = Vn + (size_t)(64 * wave + l31) * TDIM + t0;
      const unsigned short* vr1 = vr0 + (size_t)32 * TDIM;
      s16x8 va[2], vb2[2];
      va[0]  = *(const s16x8*)(vr0 + 8 * lhi);
      vb2[0] = *(const s16x8*)(vr1 + 8 * lhi);
      va[1]  = *(const s16x8*)(vr0 + 16 + 8 * lhi);
      vb2[1] = *(const s16x8*)(vr1 + 16 + 8 * lhi);
      const int prow0 = l31;
      const int prow1 = 32 + l31;
      const int psw0 = (prow0 & 15) << 3;
      const int psw1 = (prow1 & 15) << 3;
      #pragma unroll
      for (int ks = 0; ks < 8; ++ks) {
        const int kk = ks * 16 + 8 * lhi;
        s16x8 pa[2];
        {
          s16x4 x0 = *(const s16x4*)&Ps[prow0 * 128 + (kk ^ psw0)];
          s16x4 x1 = *(const s16x4*)&Ps[prow0 * 128 + ((kk + 4) ^ psw0)];
          pa[0] = __builtin_shufflevector(x0, x1, 0, 1, 2, 3, 4, 5, 6, 7);
          s16x4 y0 = *(const s16x4*)&Ps[prow1 * 128 + (kk ^ psw1)];
          s16x4 y1 = *(const s16x4*)&Ps[prow1 * 128 + ((kk + 4) ^ psw1)];
          pa[1] = __builtin_shufflevector(y0, y1, 0, 1, 2, 3, 4, 5, 6, 7);
        }
        s16x8 b0 = va[ks & 1];
        s16x8 b1 = vb2[ks & 1];
        if (ks < 6) {
          va[ks & 1]  = *(const s16x8*)(vr0 + (ks + 2) * 16 + 8 * lhi);
          vb2[ks & 1] = *(const s16x8*)(vr1 + (ks + 2) * 16 + 8 * lhi);
        }
        __builtin_amdgcn_s_setprio(1);     // T5: MFMA quad
        o_acc[0][0] = __builtin_amdgcn_mfma_f32_32x32x16_bf16(pa[0], b0, o_acc[0][0], 0, 0, 0);
        o_acc[1][0] = __builtin_amdgcn_mfma_f32_32x32x16_bf16(pa[1], b0, o_acc[1][0], 0, 0, 0);
        o_acc[0][1] = __builtin_amdgcn_mfma_f32_32x32x16_bf16(pa[0], b1, o_acc[0][1], 0, 0, 0);
        o_acc[1][1] = __builtin_amdgcn_mfma_f32_32x32x16_bf16(pa[1], b1, o_acc[1][1], 0, 0, 0);
        __builtin_amdgcn_s_setprio(0);
      }
    }

    // tb-end barrier: all waves' Ps reads done before next tb's kit0 issues
    // DMA into the free buffer (= Ps alias). lgkm-only: in-flight vmem stays.
    LGKM_BARRIER();
  }

  // ---- epilogue: drain trailing (clamped) prefetches, normalize + store ----
  asm volatile("s_waitcnt vmcnt(0) lgkmcnt(0)\n\ts_barrier" ::: "memory");
  if (tid < 64) invZ[tid] = 1.0f / Zacc[tid];
  LGKM_BARRIER();

  float* outn = out + (size_t)n * DDIM * CDIM + c0;
  for (int ch = 0; ch < 4; ++ch) {          // d-chunk of 128
    if ((wave >> 1) == ch) {
      const int s = wave & 1;
      #pragma unroll
      for (int ci = 0; ci < 2; ++ci)
        #pragma unroll
        for (int dt = 0; dt < 2; ++dt)
          #pragma unroll
          for (int rg = 0; rg < 16; ++rg) {
            const int c_loc = 32 * ci + (rg & 3) + 8 * (rg >> 2) + 4 * lhi;
            const int ddl = 64 * s + 32 * dt + l31;
            Obuf[c_loc * 129 + ddl] = o_acc[ci][dt][rg] * invZ[c_loc];
          }
    }
    LGKM_BARRIER();
    {
      const int c  = tid & 63;
      const int db = tid >> 6;
      #pragma unroll
      for (int p = 0; p < 16; ++p) {
        const int ddl = db + 8 * p;
        outn[(size_t)(128 * ch + ddl) * CDIM + c] = Obuf[c * 129 + ddl];
      }
    }
    LGKM_BARRIER();
  }
}

// ===========================================================================
// FALLBACK PATH — previous session's harness-verified kernel (545.3 µs),
// used only if ws_size is too small for the workspace path.
// ===========================================================================
#define FB_AS_OFF 0
#define FB_BS_OFF 8704
#define FB_PS_OFF 26112
#define FB_ZA_OFF 43008
#define FB_IZ_OFF 43264
#define FB_SMEM_BYTES 43520

struct QKRegs { f32x4 q0, q1, ka0, ka1, kb0, kb1; };
struct VRegs  { f32x4 a0, a1, b0, b1; };

__device__ __forceinline__ void issue_qk(QKRegs& r,
                                         const float* __restrict__ qbase,
                                         const float* __restrict__ kbase,
                                         int k0, int t0,
                                         int a_mg, int a_kq, int b_tg, int b_kq) {
  const float* gq = qbase + (size_t)(k0 + 2 * a_kq) * CDIM + 4 * a_mg;
  r.q0 = *(const f32x4*)gq;
  r.q1 = *(const f32x4*)(gq + CDIM);
  const float* gk0 = kbase + (size_t)(k0 + 2 * b_kq) * TDIM + t0 + 4 * b_tg;
  const float* gk1 = gk0 + (size_t)32 * TDIM;
  r.ka0 = *(const f32x4*)gk0;
  r.ka1 = *(const f32x4*)(gk0 + TDIM);
  r.kb0 = *(const f32x4*)gk1;
  r.kb1 = *(const f32x4*)(gk1 + TDIM);
}

__device__ __forceinline__ void issue_v(VRegs& r,
                                        const float* __restrict__ vrow0,
                                        int ks, int lhi) {
  const int kk = ks * 16 + 8 * lhi;
  const float* vp0 = vrow0 + kk;
  r.a0 = *(const f32x4*)vp0;
  r.a1 = *(const f32x4*)(vp0 + 4);
  const float* vp1 = vp0 + (size_t)32 * TDIM;
  r.b0 = *(const f32x4*)vp1;
  r.b1 = *(const f32x4*)(vp1 + 4);
}

__device__ __forceinline__ s16x8 cvt_bv(const f32x4& x0, const f32x4& x1) {
  s16x8 bv;
  bv[0] = (short)f2bf(x0[0]); bv[1] = (short)f2bf(x0[1]);
  bv[2] = (short)f2bf(x0[2]); bv[3] = (short)f2bf(x0[3]);
  bv[4] = (short)f2bf(x1[0]); bv[5] = (short)f2bf(x1[1]);
  bv[6] = (short)f2bf(x1[2]); bv[7] = (short)f2bf(x1[3]);
  return bv;
}

__global__ __launch_bounds__(512, 1)
void attn_fused_fallback(const float* __restrict__ query,
                         const float* __restrict__ key,
                         const float* __restrict__ value,
                         const float* __restrict__ ratios,
                         float* __restrict__ out)
{
  __shared__ __align__(16) char smem[FB_SMEM_BYTES];
  unsigned short* As = (unsigned short*)(smem + FB_AS_OFF);
  unsigned short* Bs = (unsigned short*)(smem + FB_BS_OFF);
  unsigned short* Ps = (unsigned short*)(smem + FB_PS_OFF);
  float* Zacc = (float*)(smem + FB_ZA_OFF);
  float* invZ = (float*)(smem + FB_IZ_OFF);
  float* Obuf = (float*)(smem + FB_AS_OFF);

  const int lin  = blockIdx.x + (int)gridDim.x * blockIdx.y;  // 0..511
  const int n    = 8 * (lin & 7) + (lin >> 6);
  const int c0   = ((lin >> 3) & 7) * CB;

  const int tid  = threadIdx.x;
  const int wave = tid >> 6;
  const int lane = tid & 63;
  const int l31  = lane & 31;
  const int lhi  = lane >> 5;

  float r = ratios[n];
  int vw = (int)floorf(128.0f * r + 0.5f);
  if (vw > 128) vw = 128;

  if (tid < 64) Zacc[tid] = 0.0f;

  const float* qbase = query + (size_t)n * DDIM * CDIM + c0;
  const float* kbase = key   + (size_t)n * DDIM * TDIM;
  const float* vbase = value + (size_t)n * DDIM * TDIM;

  f32x16 o_acc[2][2];
  #pragma unroll
  for (int a = 0; a < 2; ++a)
    #pragma unroll
    for (int b = 0; b < 2; ++b)
      #pragma unroll
      for (int i = 0; i < 16; ++i) o_acc[a][b][i] = 0.0f;

  const int p1_ct = wave & 1;
  const int p1_tt = wave >> 1;
  const int a_mg = tid & 15, a_kq = tid >> 4;
  const int b_tg = tid & 31, b_kq = tid >> 5;
  const float* vrow0_base = vbase + (size_t)(64 * wave + l31) * TDIM;

  QKRegs buf[2];
  issue_qk(buf[0], qbase, kbase, 0,  0, a_mg, a_kq, b_tg, b_kq);
  issue_qk(buf[1], qbase, kbase, BK, 0, a_mg, a_kq, b_tg, b_kq);

  LGKM_BARRIER();

  for (int tb = 0; tb < 8; ++tb) {
    const int t0 = tb * TBLK;
    f32x16 s_acc;
    #pragma unroll
    for (int i = 0; i < 16; ++i) s_acc[i] = 0.0f;

    #pragma unroll
    for (int kit = 0; kit < 8; ++kit) {
      const int g = tb * 8 + kit;
      QKRegs& rb = buf[kit & 1];

      LGKM_BARRIER();

      #pragma unroll
      for (int j = 0; j < 4; ++j) {
        unsigned int pk = (unsigned int)f2bf(rb.q0[j]) | ((unsigned int)f2bf(rb.q1[j]) << 16);
        *(unsigned int*)&As[(4 * a_mg + j) * 68 + 2 * a_kq] = pk;
      }
      #pragma unroll
      for (int j = 0; j < 4; ++j) {
        unsigned int p0 = (unsigned int)f2bf(rb.ka0[j]) | ((unsigned int)f2bf(rb.ka1[j]) << 16);
        unsigned int p1 = (unsigned int)f2bf(rb.kb0[j]) | ((unsigned int)f2bf(rb.kb1[j]) << 16);
        *(unsigned int*)&Bs[(4 * b_tg + j) * 68 + 2 * b_kq]      = p0;
        *(unsigned int*)&Bs[(4 * b_tg + j) * 68 + 2 * b_kq + 32] = p1;
      }

      {
        int gg = g + 2; if (gg > 63) gg = 63;
        issue_qk(rb, qbase, kbase, (gg & 7) * BK, (gg >> 3) * TBLK,
                 a_mg, a_kq, b_tg, b_kq);
      }

      LGKM_BARRIER();

      const int arow = (32 * p1_ct + l31) * 68;
      const int brow = (32 * p1_tt + l31) * 68;
      #pragma unroll
      for (int ks = 0; ks < 4; ++ks) {
        const int koff = ks * 16 + 8 * lhi;
        s16x4 a0 = *(const s16x4*)&As[arow + koff];
        s16x4 a1 = *(const s16x4*)&As[arow + koff + 4];
        s16x4 b0 = *(const s16x4*)&Bs[brow + koff];
        s16x4 b1 = *(const s16x4*)&Bs[brow + koff + 4];
        s16x8 av = __builtin_shufflevector(a0, a1, 0, 1, 2, 3, 4, 5, 6, 7);
        s16x8 bv = __builtin_shufflevector(b0, b1, 0, 1, 2, 3, 4, 5, 6, 7);
        s_acc = __builtin_amdgcn_mfma_f32_32x32x16_bf16(av, bv, s_acc, 0, 0, 0);
      }
    }

    {
      const int tcol = 32 * p1_tt + l31;
      const float pm = (tcol < vw) ? 1.0f : 0.0f;
      #pragma unroll
      for (int rg = 0; rg < 16; ++rg) {
        const int c_loc = 32 * p1_ct + (rg & 3) + 8 * (rg >> 2) + 4 * lhi;
        float p = pm * __expf(s_acc[rg] * SCALE);
        Ps[c_loc * 132 + tcol] = f2bf(p);
      }
    }
    LGKM_BARRIER();

    {
      const int zr = tid >> 3;
      const int zo = (tid & 7) * 16;
      float zs = 0.0f;
      #pragma unroll
      for (int j = 0; j < 16; ++j) zs += bf2f(Ps[zr * 132 + zo + j]);
      zs += __shfl_xor(zs, 1);
      zs += __shfl_xor(zs, 2);
      zs += __shfl_xor(zs, 4);
      if ((tid & 7) == 0) Zacc[zr] += zs;
    }

    {
      const float* vrow0 = vrow0_base + t0;
      VRegs vb[2];
      issue_v(vb[0], vrow0, 0, lhi);
      issue_v(vb[1], vrow0, 1, lhi);
      #pragma unroll
      for (int ks = 0; ks < 8; ++ks) {
        const int kk = ks * 16 + 8 * lhi;
        s16x8 pa[2];
        #pragma unroll
        for (int ci = 0; ci < 2; ++ci) {
          const int row = (32 * ci + l31) * 132;
          s16x4 x0 = *(const s16x4*)&Ps[row + kk];
          s16x4 x1 = *(const s16x4*)&Ps[row + kk + 4];
          pa[ci] = __builtin_shufflevector(x0, x1, 0, 1, 2, 3, 4, 5, 6, 7);
        }
        VRegs& vr = vb[ks & 1];
        s16x8 bv0 = cvt_bv(vr.a0, vr.a1);
        s16x8 bv1 = cvt_bv(vr.b0, vr.b1);
        if (ks < 6) issue_v(vr, vrow0, ks + 2, lhi);
        o_acc[0][0] = __builtin_amdgcn_mfma_f32_32x32x16_bf16(pa[0], bv0, o_acc[0][0], 0, 0, 0);
        o_acc[1][0] = __builtin_amdgcn_mfma_f32_32x32x16_bf16(pa[1], bv0, o_acc[1][0], 0, 0, 0);
        o_acc[0][1] = __builtin_amdgcn_mfma_f32_32x32x16_bf16(pa[0], bv1, o_acc[0][1], 0, 0, 0);
        o_acc[1][1] = __builtin_amdgcn_mfma_f32_32x32x16_bf16(pa[1], bv1, o_acc[1][1], 0, 0, 0);
      }
    }
  }

  LGKM_BARRIER();
  if (tid < 64) invZ[tid] = 1.0f / Zacc[tid];
  LGKM_BARRIER();

  float* outn = out + (size_t)n * DDIM * CDIM + c0;
  for (int ch = 0; ch < 4; ++ch) {
    if ((wave >> 1) == ch) {
      const int s = wave & 1;
      #pragma unroll
      for (int ci = 0; ci < 2; ++ci)
        #pragma unroll
        for (int dt = 0; dt < 2; ++dt)
          #pragma unroll
          for (int rg = 0; rg < 16; ++rg) {
            const int c_loc = 32 * ci + (rg & 3) + 8 * (rg >> 2) + 4 * lhi;
            const int ddl = 64 * s + 32 * dt + l31;
            Obuf[c_loc * 129 + ddl] = o_acc[ci][dt][rg] * invZ[c_loc];
          }
    }
    LGKM_BARRIER();
    {
      const int c = tid & 63;
      const int db = tid >> 6;
      #pragma unroll
      for (int p = 0; p < 16; ++p) {
        const int ddl = db + 8 * p;
        outn[(size_t)(128 * ch + ddl) * CDIM + c] = Obuf[c * 129 + ddl];
      }
    }
    LGKM_BARRIER();
  }
}

extern "C" void kernel_launch(void* const* d_in, const int* in_sizes, int n_in,
                              void* d_out, int out_size, void* d_ws, size_t ws_size,
                              hipStream_t stream) {
  const float* query  = (const float*)d_in[0];
  const float* key    = (const float*)d_in[1];
  const float* value  = (const float*)d_in[2];
  const float* ratios = (const float*)d_in[3];
  float* out = (float*)d_out;
  (void)in_sizes; (void)n_in; (void)out_size;

  // workspace: Qt (32 MB) | Kt (64 MB) | Vb (64 MB)  => 160 MB bf16 total
  const size_t needQ = (size_t)NS * CDIM * DDIM;       // shorts
  const size_t needK = (size_t)NS * TDIM * DDIM;       // shorts
  const size_t needV = (size_t)NS * DDIM * TDIM;       // shorts
  const size_t need_bytes = (needQ + needK + needV) * sizeof(unsigned short);

  if (d_ws != nullptr && ws_size >= need_bytes) {
    unsigned short* Qt = (unsigned short*)d_ws;
    unsigned short* Kt = Qt + needQ;
    unsigned short* Vb = Kt + needK;
    prep_kernel<<<dim3(14336), 256, 0, stream>>>(query, key, value, Qt, Kt, Vb);
    attn_main<<<dim3(CDIM / CB, NS), 512, 0, stream>>>(Qt, Kt, Vb, ratios, out);
  } else {
    attn_fused_fallback<<<dim3(CDIM / CB, NS), 512, 0, stream>>>(query, key, value, ratios, out);
  }
}

// Round 9
// 528.098 us; speedup vs baseline: 3.0674x; 1.1088x over previous
//
#include <hip/hip_runtime.h>

// Problem constants (shapes fixed by reference setup_inputs)
#define NS   64
#define DDIM 512
#define CDIM 512
#define TDIM 1024
#define CB   64     // c-rows per workgroup
#define TBLK 128    // t-tile per outer iteration (== w)
#define BK   64     // k(d)-chunk staged per inner iteration
#define SCALE 0.04419417382415922f   // 512^-0.5

typedef __attribute__((ext_vector_type(4)))  float f32x4;
typedef __attribute__((ext_vector_type(16))) float f32x16;
typedef __attribute__((ext_vector_type(4)))  short s16x4;
typedef __attribute__((ext_vector_type(8)))  short s16x8;

// Barrier that orders LDS only — does NOT drain vmcnt, so global prefetches
// stay in flight across it.
#define LGKM_BARRIER() asm volatile("s_waitcnt lgkmcnt(0)\n\ts_barrier" ::: "memory")

// fp32 -> bf16 bits, round-to-nearest-even
__device__ __forceinline__ unsigned short f2bf(float f) {
  unsigned int b = __float_as_uint(f);
  return (unsigned short)((b + 0x7FFFu + ((b >> 16) & 1u)) >> 16);
}
__device__ __forceinline__ float bf2f(unsigned short u) {
  return __uint_as_float(((unsigned int)u) << 16);
}

// 16B async global->LDS (DMA; LDS dest = wave-uniform base + lane*16)
__device__ __forceinline__ void gload_lds16(const void* g, void* l) {
  __builtin_amdgcn_global_load_lds(
      (const __attribute__((address_space(1))) unsigned int*)g,
      (__attribute__((address_space(3))) unsigned int*)l, 16, 0, 0);
}

// ===========================================================================
// FUSED PRE-PASS (unchanged from Round-5 verified run): one kernel, 3 jobs.
// ===========================================================================
__global__ __launch_bounds__(256)
void prep_kernel(const float* __restrict__ query,
                 const float* __restrict__ key,
                 const float* __restrict__ value,
                 unsigned short* __restrict__ Qt,
                 unsigned short* __restrict__ Kt,
                 unsigned short* __restrict__ Vb)
{
  __shared__ float tile[64 * 65];
  const int b   = blockIdx.x;
  const int tid = threadIdx.x;

  if (b < 12288) {
    // ---- transpose-convert job ----
    const float* src; unsigned short* dst; int C, n, rb, cb;
    if (b < 4096) {              // Q: grid 8(cb) x 8(rb) x 64(n)
      const int local = b;
      C = CDIM; cb = (local & 7) * 64; rb = ((local >> 3) & 7) * 64;
      n = local >> 6; src = query; dst = Qt;
    } else {                     // K: grid 16(cb) x 8(rb) x 64(n)
      const int local = b - 4096;
      C = TDIM; cb = (local & 15) * 64; rb = ((local >> 4) & 7) * 64;
      n = local >> 7; src = key; dst = Kt;
    }
    const float* s = src + (size_t)n * 512 * C + (size_t)rb * C + cb;
    #pragma unroll
    for (int i = 0; i < 4; ++i) {
      const int idx = i * 256 + tid;
      const int r   = idx >> 4;               // 0..63 (d within tile)
      const int c4  = (idx & 15) << 2;        // 0,4..60 (c within tile)
      f32x4 v = *(const f32x4*)(s + (size_t)r * C + c4);
      tile[(c4 + 0) * 65 + r] = v[0];
      tile[(c4 + 1) * 65 + r] = v[1];
      tile[(c4 + 2) * 65 + r] = v[2];
      tile[(c4 + 3) * 65 + r] = v[3];
    }
    __syncthreads();
    unsigned short* d = dst + (size_t)n * 512 * C + (size_t)cb * 512 + rb;
    #pragma unroll
    for (int i = 0; i < 2; ++i) {
      const int idx = i * 256 + tid;
      const int c   = idx >> 3;               // 0..63
      const int r8  = (idx & 7) << 3;         // 0,8..56
      s16x8 o;
      #pragma unroll
      for (int j = 0; j < 8; ++j) o[j] = (short)f2bf(tile[c * 65 + r8 + j]);
      *(s16x8*)(d + (size_t)c * 512 + r8) = o;
    }
  } else {
    // ---- V convert job: 2048 blocks x 16384 elems, fully coalesced ----
    const int vb = b - 12288;
    const size_t base = (size_t)vb * 16384;
    #pragma unroll
    for (int i = 0; i < 8; ++i) {
      const size_t off = base + (size_t)i * 2048 + (size_t)tid * 8;
      f32x4 v0 = *(const f32x4*)(value + off);
      f32x4 v1 = *(const f32x4*)(value + off + 4);
      s16x8 o;
      o[0] = (short)f2bf(v0[0]); o[1] = (short)f2bf(v0[1]);
      o[2] = (short)f2bf(v0[2]); o[3] = (short)f2bf(v0[3]);
      o[4] = (short)f2bf(v1[0]); o[5] = (short)f2bf(v1[1]);
      o[6] = (short)f2bf(v1[2]); o[7] = (short)f2bf(v1[3]);
      *(s16x8*)(Vb + off) = o;
    }
  }
}

// ---------------------------------------------------------------------------
// Main fused kernel — R8: REVERT to the R3-exact structure (measured 198 µs
// in R3 and R5; R6 spilled via launch_bounds cap, R7's depth-2 tri-buffer
// added +230 MB HBM traffic and regressed to 250 µs). Register model: at
// (512,4) the unified budget is 128 = 64 VGPR + 64 AGPR exactly — zero
// headroom, so no change may add registers. Single A/B vs R3: s_setprio
// REMOVED from phase 1 (8-wave barrier-locked lockstep -> T5 null/negative
// regime, m190); phase 3 keeps setprio (wave-independent, T5-positive regime).
// LDS layout (bytes):
//   As0 @ 0      [64][128B]  bf16 Q-tile (XOR-swizzled content, linear layout)
//   As1 @ 8192
//   Bs0 @ 16384  [128][128B] bf16 K-tile
//   Bs1 @ 32768
//   Ps  @ 49152  [64][132] bf16  P-tile (padded stride: PV reads 2-way only)
//   Zacc@ 66048  [64] f32 ; invZ @ 66304 [64] f32
//   Obuf@ 0      [64][129] f32 (epilogue, overlaps As/Bs after full drain)
// ---------------------------------------------------------------------------
#define AS0_OFF 0
#define AS1_OFF 8192
#define BS0_OFF 16384
#define BS1_OFF 32768
#define PS_OFF  49152
#define ZA_OFF  66048
#define IZ_OFF  66304
#define SMEM_BYTES 66560

// Stage chunk g (k0 = (g&7)*64, t0 = (g>>3)*128): As 1 issue + Bs 2 issues,
// 16B/lane. Source address carries the XOR swizzle (byte ^= (row&7)<<4) so
// LDS stays linear (global_load_lds requirement) and the swizzled
// ds_read_b128 on the consume side is bank-conflict-spread (rule #21: the
// source permutation and the read permutation are the same involution).
__device__ __forceinline__ void issue_tiles(const char* __restrict__ Qn,
                                            const char* __restrict__ Kn,
                                            char* as_lds, char* bs_lds,
                                            int g, int tid) {
  if (g > 63) g = 63;                       // clamped re-issue (harmless dup)
  const int k0b = (g & 7) * (BK * 2);
  const int t0  = (g >> 3) * TBLK;
  {
    const int row  = tid >> 3;              // c row 0..63
    const int colb = ((tid & 7) << 4) ^ ((row & 7) << 4);
    gload_lds16(Qn + (size_t)row * (DDIM * 2) + k0b + colb, as_lds + tid * 16);
  }
  #pragma unroll
  for (int i = 0; i < 2; ++i) {
    const int idx  = i * 512 + tid;
    const int row  = idx >> 3;              // t row 0..127
    const int colb = ((idx & 7) << 4) ^ ((row & 7) << 4);
    gload_lds16(Kn + (size_t)(t0 + row) * (DDIM * 2) + k0b + colb, bs_lds + idx * 16);
  }
}

__global__ __launch_bounds__(512, 4)   // 2 blocks/CU; 128-reg unified budget
void attn_main(const unsigned short* __restrict__ Qt,   // [n][c][d] bf16
               const unsigned short* __restrict__ Kt,   // [n][t][d] bf16
               const unsigned short* __restrict__ Vb,   // [n][d][t] bf16
               const float* __restrict__ ratios,
               float* __restrict__ out)
{
  __shared__ __align__(16) char smem[SMEM_BYTES];
  unsigned short* Ps = (unsigned short*)(smem + PS_OFF);
  float* Zacc = (float*)(smem + ZA_OFF);
  float* invZ = (float*)(smem + IZ_OFF);
  float* Obuf = (float*)smem;

  // XCD swizzle: all 8 c-blocks of one sample -> same XCD (same L2)
  const int lin = blockIdx.x + (int)gridDim.x * blockIdx.y;  // 0..511
  const int n   = 8 * (lin & 7) + (lin >> 6);
  const int c0  = ((lin >> 3) & 7) * CB;

  const int tid  = threadIdx.x;
  const int wave = tid >> 6;
  const int lane = tid & 63;
  const int l31  = lane & 31;
  const int lhi  = lane >> 5;

  float r = ratios[n];
  int vw = (int)floorf(128.0f * r + 0.5f);
  if (vw > 128) vw = 128;

  const char* Qn = (const char*)(Qt + (size_t)n * CDIM * DDIM + (size_t)c0 * DDIM);
  const char* Kn = (const char*)(Kt + (size_t)n * TDIM * DDIM);
  const unsigned short* Vn = Vb + (size_t)n * DDIM * TDIM;

  f32x16 o_acc[2][2];
  #pragma unroll
  for (int a = 0; a < 2; ++a)
    #pragma unroll
    for (int b = 0; b < 2; ++b)
      #pragma unroll
      for (int i = 0; i < 16; ++i) o_acc[a][b][i] = 0.0f;

  const int p1_ct = wave & 1;   // c strip (2 x 32)
  const int p1_tt = wave >> 1;  // t strip (4 x 32)

  if (tid < 64) Zacc[tid] = 0.0f;
  issue_tiles(Qn, Kn, smem + AS0_OFF, smem + BS0_OFF, 0, tid);
  // order Zacc init; do NOT drain vmcnt (prefetch stays in flight)
  LGKM_BARRIER();

  const int swz = (l31 & 7) << 4;
  const int aro = (32 * p1_ct + l31) * 128;
  const int bro = (32 * p1_tt + l31) * 128;

  for (int tb = 0; tb < 8; ++tb) {
    const int t0 = tb * TBLK;
    f32x16 s_acc;
    #pragma unroll
    for (int i = 0; i < 16; ++i) s_acc[i] = 0.0f;

    // ---- phase 1: S(64x128) += Q^T K over d; DMA-staged, dbuf, vmcnt(3) ----
    #pragma unroll
    for (int kit = 0; kit < 8; ++kit) {
      const int g = tb * 8 + kit;           // (g&1) == (kit&1) since 8|tb*8
      char* asb = smem + ((kit & 1) ? AS1_OFF : AS0_OFF);
      char* bsb = smem + ((kit & 1) ? BS1_OFF : BS0_OFF);
      char* asn = smem + ((kit & 1) ? AS0_OFF : AS1_OFF);
      char* bsn = smem + ((kit & 1) ? BS0_OFF : BS1_OFF);
      // prefetch next chunk into the buffer every wave finished reading last kit
      issue_tiles(Qn, Kn, asn, bsn, g + 1, tid);
      // wait for CURRENT chunk's 3 loads only (3 newer stay in flight)
      asm volatile("s_waitcnt vmcnt(3)\n\ts_barrier" ::: "memory");
      // NOTE: no setprio here (R8 A/B) — 8-wave lockstep loop, T5-null regime
      #pragma unroll
      for (int ks = 0; ks < 4; ++ks) {
        const int coff = (ks * 32 + 16 * lhi) ^ swz;
        s16x8 av = *(const s16x8*)(asb + aro + coff);
        s16x8 bv = *(const s16x8*)(bsb + bro + coff);
        s_acc = __builtin_amdgcn_mfma_f32_32x32x16_bf16(av, bv, s_acc, 0, 0, 0);
      }
      // drain frag reads so next kit may overwrite this buffer (no vmcnt drain)
      LGKM_BARRIER();
    }

    // ---- phase 2: p = mask * exp(s*scale) ----
    {
      const int tcol = 32 * p1_tt + l31;
      const float pm = (tcol < vw) ? 1.0f : 0.0f;
      #pragma unroll
      for (int rg = 0; rg < 16; ++rg) {
        const int c_loc = 32 * p1_ct + (rg & 3) + 8 * (rg >> 2) + 4 * lhi;
        float p = pm * __expf(s_acc[rg] * SCALE);
        Ps[c_loc * 132 + tcol] = f2bf(p);
      }
    }
    LGKM_BARRIER();

    // ---- Z row-sum accumulation (vectorized b64 reads) ----
    {
      const int zr = tid >> 3;
      const int zo = (tid & 7) * 16;
      float zs = 0.0f;
      #pragma unroll
      for (int j4 = 0; j4 < 4; ++j4) {
        s16x4 v4 = *(const s16x4*)&Ps[zr * 132 + zo + 4 * j4];
        zs += bf2f((unsigned short)v4[0]) + bf2f((unsigned short)v4[1])
            + bf2f((unsigned short)v4[2]) + bf2f((unsigned short)v4[3]);
      }
      zs += __shfl_xor(zs, 1);
      zs += __shfl_xor(zs, 2);
      zs += __shfl_xor(zs, 4);
      if ((tid & 7) == 0) Zacc[zr] += zs;
    }

    // ---- phase 3: O += P * V^T ; V direct bf16 from global, dist-2 prefetch ----
    {
      const unsigned short* vr0 = Vn + (size_t)(64 * wave + l31) * TDIM + t0;
      const unsigned short* vr1 = vr0 + (size_t)32 * TDIM;
      s16x8 va[2], vb2[2];
      va[0]  = *(const s16x8*)(vr0 + 8 * lhi);
      vb2[0] = *(const s16x8*)(vr1 + 8 * lhi);
      va[1]  = *(const s16x8*)(vr0 + 16 + 8 * lhi);
      vb2[1] = *(const s16x8*)(vr1 + 16 + 8 * lhi);
      #pragma unroll
      for (int ks = 0; ks < 8; ++ks) {
        const int kk = ks * 16 + 8 * lhi;
        s16x8 pa[2];
        #pragma unroll
        for (int ci = 0; ci < 2; ++ci) {
          const int rowb = (32 * ci + l31) * 132;
          s16x4 x0 = *(const s16x4*)&Ps[rowb + kk];
          s16x4 x1 = *(const s16x4*)&Ps[rowb + kk + 4];
          pa[ci] = __builtin_shufflevector(x0, x1, 0, 1, 2, 3, 4, 5, 6, 7);
        }
        s16x8 b0 = va[ks & 1];
        s16x8 b1 = vb2[ks & 1];
        if (ks < 6) {
          va[ks & 1]  = *(const s16x8*)(vr0 + (ks + 2) * 16 + 8 * lhi);
          vb2[ks & 1] = *(const s16x8*)(vr1 + (ks + 2) * 16 + 8 * lhi);
        }
        __builtin_amdgcn_s_setprio(1);     // T5 kept: wave-independent phase
        o_acc[0][0] = __builtin_amdgcn_mfma_f32_32x32x16_bf16(pa[0], b0, o_acc[0][0], 0, 0, 0);
        o_acc[1][0] = __builtin_amdgcn_mfma_f32_32x32x16_bf16(pa[1], b0, o_acc[1][0], 0, 0, 0);
        o_acc[0][1] = __builtin_amdgcn_mfma_f32_32x32x16_bf16(pa[0], b1, o_acc[0][1], 0, 0, 0);
        o_acc[1][1] = __builtin_amdgcn_mfma_f32_32x32x16_bf16(pa[1], b1, o_acc[1][1], 0, 0, 0);
        __builtin_amdgcn_s_setprio(0);
      }
    }
  }

  // ---- epilogue: drain the clamped trailing prefetch, then normalize+store ----
  asm volatile("s_waitcnt vmcnt(0) lgkmcnt(0)\n\ts_barrier" ::: "memory");
  if (tid < 64) invZ[tid] = 1.0f / Zacc[tid];
  LGKM_BARRIER();

  float* outn = out + (size_t)n * DDIM * CDIM + c0;
  for (int ch = 0; ch < 4; ++ch) {          // d-chunk of 128
    if ((wave >> 1) == ch) {
      const int s = wave & 1;
      #pragma unroll
      for (int ci = 0; ci < 2; ++ci)
        #pragma unroll
        for (int dt = 0; dt < 2; ++dt)
          #pragma unroll
          for (int rg = 0; rg < 16; ++rg) {
            const int c_loc = 32 * ci + (rg & 3) + 8 * (rg >> 2) + 4 * lhi;
            const int ddl = 64 * s + 32 * dt + l31;
            Obuf[c_loc * 129 + ddl] = o_acc[ci][dt][rg] * invZ[c_loc];
          }
    }
    LGKM_BARRIER();
    {
      const int c  = tid & 63;
      const int db = tid >> 6;
      #pragma unroll
      for (int p = 0; p < 16; ++p) {
        const int ddl = db + 8 * p;
        outn[(size_t)(128 * ch + ddl) * CDIM + c] = Obuf[c * 129 + ddl];
      }
    }
    LGKM_BARRIER();
  }
}

// ===========================================================================
// FALLBACK PATH — previous session's harness-verified kernel (545.3 µs),
// used only if ws_size is too small for the workspace path.
// ===========================================================================
#define FB_AS_OFF 0
#define FB_BS_OFF 8704
#define FB_PS_OFF 26112
#define FB_ZA_OFF 43008
#define FB_IZ_OFF 43264
#define FB_SMEM_BYTES 43520

struct QKRegs { f32x4 q0, q1, ka0, ka1, kb0, kb1; };
struct VRegs  { f32x4 a0, a1, b0, b1; };

__device__ __forceinline__ void issue_qk(QKRegs& r,
                                         const float* __restrict__ qbase,
                                         const float* __restrict__ kbase,
                                         int k0, int t0,
                                         int a_mg, int a_kq, int b_tg, int b_kq) {
  const float* gq = qbase + (size_t)(k0 + 2 * a_kq) * CDIM + 4 * a_mg;
  r.q0 = *(const f32x4*)gq;
  r.q1 = *(const f32x4*)(gq + CDIM);
  const float* gk0 = kbase + (size_t)(k0 + 2 * b_kq) * TDIM + t0 + 4 * b_tg;
  const float* gk1 = gk0 + (size_t)32 * TDIM;
  r.ka0 = *(const f32x4*)gk0;
  r.ka1 = *(const f32x4*)(gk0 + TDIM);
  r.kb0 = *(const f32x4*)gk1;
  r.kb1 = *(const f32x4*)(gk1 + TDIM);
}

__device__ __forceinline__ void issue_v(VRegs& r,
                                        const float* __restrict__ vrow0,
                                        int ks, int lhi) {
  const int kk = ks * 16 + 8 * lhi;
  const float* vp0 = vrow0 + kk;
  r.a0 = *(const f32x4*)vp0;
  r.a1 = *(const f32x4*)(vp0 + 4);
  const float* vp1 = vp0 + (size_t)32 * TDIM;
  r.b0 = *(const f32x4*)vp1;
  r.b1 = *(const f32x4*)(vp1 + 4);
}

__device__ __forceinline__ s16x8 cvt_bv(const f32x4& x0, const f32x4& x1) {
  s16x8 bv;
  bv[0] = (short)f2bf(x0[0]); bv[1] = (short)f2bf(x0[1]);
  bv[2] = (short)f2bf(x0[2]); bv[3] = (short)f2bf(x0[3]);
  bv[4] = (short)f2bf(x1[0]); bv[5] = (short)f2bf(x1[1]);
  bv[6] = (short)f2bf(x1[2]); bv[7] = (short)f2bf(x1[3]);
  return bv;
}

__global__ __launch_bounds__(512, 1)
void attn_fused_fallback(const float* __restrict__ query,
                         const float* __restrict__ key,
                         const float* __restrict__ value,
                         const float* __restrict__ ratios,
                         float* __restrict__ out)
{
  __shared__ __align__(16) char smem[FB_SMEM_BYTES];
  unsigned short* As = (unsigned short*)(smem + FB_AS_OFF);
  unsigned short* Bs = (unsigned short*)(smem + FB_BS_OFF);
  unsigned short* Ps = (unsigned short*)(smem + FB_PS_OFF);
  float* Zacc = (float*)(smem + FB_ZA_OFF);
  float* invZ = (float*)(smem + FB_IZ_OFF);
  float* Obuf = (float*)(smem + FB_AS_OFF);

  const int lin  = blockIdx.x + (int)gridDim.x * blockIdx.y;  // 0..511
  const int n    = 8 * (lin & 7) + (lin >> 6);
  const int c0   = ((lin >> 3) & 7) * CB;

  const int tid  = threadIdx.x;
  const int wave = tid >> 6;
  const int lane = tid & 63;
  const int l31  = lane & 31;
  const int lhi  = lane >> 5;

  float r = ratios[n];
  int vw = (int)floorf(128.0f * r + 0.5f);
  if (vw > 128) vw = 128;

  if (tid < 64) Zacc[tid] = 0.0f;

  const float* qbase = query + (size_t)n * DDIM * CDIM + c0;
  const float* kbase = key   + (size_t)n * DDIM * TDIM;
  const float* vbase = value + (size_t)n * DDIM * TDIM;

  f32x16 o_acc[2][2];
  #pragma unroll
  for (int a = 0; a < 2; ++a)
    #pragma unroll
    for (int b = 0; b < 2; ++b)
      #pragma unroll
      for (int i = 0; i < 16; ++i) o_acc[a][b][i] = 0.0f;

  const int p1_ct = wave & 1;
  const int p1_tt = wave >> 1;
  const int a_mg = tid & 15, a_kq = tid >> 4;
  const int b_tg = tid & 31, b_kq = tid >> 5;
  const float* vrow0_base = vbase + (size_t)(64 * wave + l31) * TDIM;

  QKRegs buf[2];
  issue_qk(buf[0], qbase, kbase, 0,  0, a_mg, a_kq, b_tg, b_kq);
  issue_qk(buf[1], qbase, kbase, BK, 0, a_mg, a_kq, b_tg, b_kq);

  LGKM_BARRIER();

  for (int tb = 0; tb < 8; ++tb) {
    const int t0 = tb * TBLK;
    f32x16 s_acc;
    #pragma unroll
    for (int i = 0; i < 16; ++i) s_acc[i] = 0.0f;

    #pragma unroll
    for (int kit = 0; kit < 8; ++kit) {
      const int g = tb * 8 + kit;
      QKRegs& rb = buf[kit & 1];

      LGKM_BARRIER();

      #pragma unroll
      for (int j = 0; j < 4; ++j) {
        unsigned int pk = (unsigned int)f2bf(rb.q0[j]) | ((unsigned int)f2bf(rb.q1[j]) << 16);
        *(unsigned int*)&As[(4 * a_mg + j) * 68 + 2 * a_kq] = pk;
      }
      #pragma unroll
      for (int j = 0; j < 4; ++j) {
        unsigned int p0 = (unsigned int)f2bf(rb.ka0[j]) | ((unsigned int)f2bf(rb.ka1[j]) << 16);
        unsigned int p1 = (unsigned int)f2bf(rb.kb0[j]) | ((unsigned int)f2bf(rb.kb1[j]) << 16);
        *(unsigned int*)&Bs[(4 * b_tg + j) * 68 + 2 * b_kq]      = p0;
        *(unsigned int*)&Bs[(4 * b_tg + j) * 68 + 2 * b_kq + 32] = p1;
      }

      {
        int gg = g + 2; if (gg > 63) gg = 63;
        issue_qk(rb, qbase, kbase, (gg & 7) * BK, (gg >> 3) * TBLK,
                 a_mg, a_kq, b_tg, b_kq);
      }

      LGKM_BARRIER();

      const int arow = (32 * p1_ct + l31) * 68;
      const int brow = (32 * p1_tt + l31) * 68;
      #pragma unroll
      for (int ks = 0; ks < 4; ++ks) {
        const int koff = ks * 16 + 8 * lhi;
        s16x4 a0 = *(const s16x4*)&As[arow + koff];
        s16x4 a1 = *(const s16x4*)&As[arow + koff + 4];
        s16x4 b0 = *(const s16x4*)&Bs[brow + koff];
        s16x4 b1 = *(const s16x4*)&Bs[brow + koff + 4];
        s16x8 av = __builtin_shufflevector(a0, a1, 0, 1, 2, 3, 4, 5, 6, 7);
        s16x8 bv = __builtin_shufflevector(b0, b1, 0, 1, 2, 3, 4, 5, 6, 7);
        s_acc = __builtin_amdgcn_mfma_f32_32x32x16_bf16(av, bv, s_acc, 0, 0, 0);
      }
    }

    {
      const int tcol = 32 * p1_tt + l31;
      const float pm = (tcol < vw) ? 1.0f : 0.0f;
      #pragma unroll
      for (int rg = 0; rg < 16; ++rg) {
        const int c_loc = 32 * p1_ct + (rg & 3) + 8 * (rg >> 2) + 4 * lhi;
        float p = pm * __expf(s_acc[rg] * SCALE);
        Ps[c_loc * 132 + tcol] = f2bf(p);
      }
    }
    LGKM_BARRIER();

    {
      const int zr = tid >> 3;
      const int zo = (tid & 7) * 16;
      float zs = 0.0f;
      #pragma unroll
      for (int j = 0; j < 16; ++j) zs += bf2f(Ps[zr * 132 + zo + j]);
      zs += __shfl_xor(zs, 1);
      zs += __shfl_xor(zs, 2);
      zs += __shfl_xor(zs, 4);
      if ((tid & 7) == 0) Zacc[zr] += zs;
    }

    {
      const float* vrow0 = vrow0_base + t0;
      VRegs vb[2];
      issue_v(vb[0], vrow0, 0, lhi);
      issue_v(vb[1], vrow0, 1, lhi);
      #pragma unroll
      for (int ks = 0; ks < 8; ++ks) {
        const int kk = ks * 16 + 8 * lhi;
        s16x8 pa[2];
        #pragma unroll
        for (int ci = 0; ci < 2; ++ci) {
          const int row = (32 * ci + l31) * 132;
          s16x4 x0 = *(const s16x4*)&Ps[row + kk];
          s16x4 x1 = *(const s16x4*)&Ps[row + kk + 4];
          pa[ci] = __builtin_shufflevector(x0, x1, 0, 1, 2, 3, 4, 5, 6, 7);
        }
        VRegs& vr = vb[ks & 1];
        s16x8 bv0 = cvt_bv(vr.a0, vr.a1);
        s16x8 bv1 = cvt_bv(vr.b0, vr.b1);
        if (ks < 6) issue_v(vr, vrow0, ks + 2, lhi);
        o_acc[0][0] = __builtin_amdgcn_mfma_f32_32x32x16_bf16(pa[0], bv0, o_acc[0][0], 0, 0, 0);
        o_acc[1][0] = __builtin_amdgcn_mfma_f32_32x32x16_bf16(pa[1], bv0, o_acc[1][0], 0, 0, 0);
        o_acc[0][1] = __builtin_amdgcn_mfma_f32_32x32x16_bf16(pa[0], bv1, o_acc[0][1], 0, 0, 0);
        o_acc[1][1] = __builtin_amdgcn_mfma_f32_32x32x16_bf16(pa[1], bv1, o_acc[1][1], 0, 0, 0);
      }
    }
  }

  LGKM_BARRIER();
  if (tid < 64) invZ[tid] = 1.0f / Zacc[tid];
  LGKM_BARRIER();

  float* outn = out + (size_t)n * DDIM * CDIM + c0;
  for (int ch = 0; ch < 4; ++ch) {
    if ((wave >> 1) == ch) {
      const int s = wave & 1;
      #pragma unroll
      for (int ci = 0; ci < 2; ++ci)
        #pragma unroll
        for (int dt = 0; dt < 2; ++dt)
          #pragma unroll
          for (int rg = 0; rg < 16; ++rg) {
            const int c_loc = 32 * ci + (rg & 3) + 8 * (rg >> 2) + 4 * lhi;
            const int ddl = 64 * s + 32 * dt + l31;
            Obuf[c_loc * 129 + ddl] = o_acc[ci][dt][rg] * invZ[c_loc];
          }
    }
    LGKM_BARRIER();
    {
      const int c = tid & 63;
      const int db = tid >> 6;
      #pragma unroll
      for (int p = 0; p < 16; ++p) {
        const int ddl = db + 8 * p;
        outn[(size_t)(128 * ch + ddl) * CDIM + c] = Obuf[c * 129 + ddl];
      }
    }
    LGKM_BARRIER();
  }
}

extern "C" void kernel_launch(void* const* d_in, const int* in_sizes, int n_in,
                              void* d_out, int out_size, void* d_ws, size_t ws_size,
                              hipStream_t stream) {
  const float* query  = (const float*)d_in[0];
  const float* key    = (const float*)d_in[1];
  const float* value  = (const float*)d_in[2];
  const float* ratios = (const float*)d_in[3];
  float* out = (float*)d_out;
  (void)in_sizes; (void)n_in; (void)out_size;

  // workspace: Qt (32 MB) | Kt (64 MB) | Vb (64 MB)  => 160 MB bf16 total
  const size_t needQ = (size_t)NS * CDIM * DDIM;       // shorts
  const size_t needK = (size_t)NS * TDIM * DDIM;       // shorts
  const size_t needV = (size_t)NS * DDIM * TDIM;       // shorts
  const size_t need_bytes = (needQ + needK + needV) * sizeof(unsigned short);

  if (d_ws != nullptr && ws_size >= need_bytes) {
    unsigned short* Qt = (unsigned short*)d_ws;
    unsigned short* Kt = Qt + needQ;
    unsigned short* Vb = Kt + needK;
    prep_kernel<<<dim3(14336), 256, 0, stream>>>(query, key, value, Qt, Kt, Vb);
    attn_main<<<dim3(CDIM / CB, NS), 512, 0, stream>>>(Qt, Kt, Vb, ratios, out);
  } else {
    attn_fused_fallback<<<dim3(CDIM / CB, NS), 512, 0, stream>>>(query, key, value, ratios, out);
  }
}

// Round 11
// 526.541 us; speedup vs baseline: 3.0765x; 1.0030x over previous
//
#include <hip/hip_runtime.h>

// Problem constants (shapes fixed by reference setup_inputs)
#define NS   64
#define DDIM 512
#define CDIM 512
#define TDIM 1024
#define CB   64     // c-rows per workgroup
#define TBLK 128    // t-tile per outer iteration (== w)
#define BK   64     // k(d)-chunk staged per inner iteration
#define SCALE 0.04419417382415922f   // 512^-0.5

typedef __attribute__((ext_vector_type(4)))  float f32x4;
typedef __attribute__((ext_vector_type(16))) float f32x16;
typedef __attribute__((ext_vector_type(4)))  short s16x4;
typedef __attribute__((ext_vector_type(8)))  short s16x8;

// Barrier that orders LDS only — does NOT drain vmcnt, so global prefetches
// stay in flight across it.
#define LGKM_BARRIER() asm volatile("s_waitcnt lgkmcnt(0)\n\ts_barrier" ::: "memory")

// fp32 -> bf16 bits, round-to-nearest-even
__device__ __forceinline__ unsigned short f2bf(float f) {
  unsigned int b = __float_as_uint(f);
  return (unsigned short)((b + 0x7FFFu + ((b >> 16) & 1u)) >> 16);
}
__device__ __forceinline__ float bf2f(unsigned short u) {
  return __uint_as_float(((unsigned int)u) << 16);
}

// 16B async global->LDS (DMA; LDS dest = wave-uniform base + lane*16)
__device__ __forceinline__ void gload_lds16(const void* g, void* l) {
  __builtin_amdgcn_global_load_lds(
      (const __attribute__((address_space(1))) unsigned int*)g,
      (__attribute__((address_space(3))) unsigned int*)l, 16, 0, 0);
}

// ===========================================================================
// FUSED PRE-PASS (unchanged from Round-5 verified run): one kernel, 3 jobs.
// ===========================================================================
__global__ __launch_bounds__(256)
void prep_kernel(const float* __restrict__ query,
                 const float* __restrict__ key,
                 const float* __restrict__ value,
                 unsigned short* __restrict__ Qt,
                 unsigned short* __restrict__ Kt,
                 unsigned short* __restrict__ Vb)
{
  __shared__ float tile[64 * 65];
  const int b   = blockIdx.x;
  const int tid = threadIdx.x;

  if (b < 12288) {
    // ---- transpose-convert job ----
    const float* src; unsigned short* dst; int C, n, rb, cb;
    if (b < 4096) {              // Q: grid 8(cb) x 8(rb) x 64(n)
      const int local = b;
      C = CDIM; cb = (local & 7) * 64; rb = ((local >> 3) & 7) * 64;
      n = local >> 6; src = query; dst = Qt;
    } else {                     // K: grid 16(cb) x 8(rb) x 64(n)
      const int local = b - 4096;
      C = TDIM; cb = (local & 15) * 64; rb = ((local >> 4) & 7) * 64;
      n = local >> 7; src = key; dst = Kt;
    }
    const float* s = src + (size_t)n * 512 * C + (size_t)rb * C + cb;
    #pragma unroll
    for (int i = 0; i < 4; ++i) {
      const int idx = i * 256 + tid;
      const int r   = idx >> 4;               // 0..63 (d within tile)
      const int c4  = (idx & 15) << 2;        // 0,4..60 (c within tile)
      f32x4 v = *(const f32x4*)(s + (size_t)r * C + c4);
      tile[(c4 + 0) * 65 + r] = v[0];
      tile[(c4 + 1) * 65 + r] = v[1];
      tile[(c4 + 2) * 65 + r] = v[2];
      tile[(c4 + 3) * 65 + r] = v[3];
    }
    __syncthreads();
    unsigned short* d = dst + (size_t)n * 512 * C + (size_t)cb * 512 + rb;
    #pragma unroll
    for (int i = 0; i < 2; ++i) {
      const int idx = i * 256 + tid;
      const int c   = idx >> 3;               // 0..63
      const int r8  = (idx & 7) << 3;         // 0,8..56
      s16x8 o;
      #pragma unroll
      for (int j = 0; j < 8; ++j) o[j] = (short)f2bf(tile[c * 65 + r8 + j]);
      *(s16x8*)(d + (size_t)c * 512 + r8) = o;
    }
  } else {
    // ---- V convert job: 2048 blocks x 16384 elems, fully coalesced ----
    const int vb = b - 12288;
    const size_t base = (size_t)vb * 16384;
    #pragma unroll
    for (int i = 0; i < 8; ++i) {
      const size_t off = base + (size_t)i * 2048 + (size_t)tid * 8;
      f32x4 v0 = *(const f32x4*)(value + off);
      f32x4 v1 = *(const f32x4*)(value + off + 4);
      s16x8 o;
      o[0] = (short)f2bf(v0[0]); o[1] = (short)f2bf(v0[1]);
      o[2] = (short)f2bf(v0[2]); o[3] = (short)f2bf(v0[3]);
      o[4] = (short)f2bf(v1[0]); o[5] = (short)f2bf(v1[1]);
      o[6] = (short)f2bf(v1[2]); o[7] = (short)f2bf(v1[3]);
      *(s16x8*)(Vb + off) = o;
    }
  }
}

// ---------------------------------------------------------------------------
// Main fused kernel — R10: tri-buffer DEPTH-1 (R9's schedule, minus the
// trailing per-kit lgkm-barrier). Buffer X computed at kit g is overwritten
// only at kit g+3's prefetch; the two intervening vmcnt(3)+barrier sync
// points already order all waves' ds_reads (reads retire via the compiler's
// lgkmcnt before the consuming MFMA, which precedes the next barrier).
// Phase-1 barriers: 16/tb -> 8/tb. Prefetch distance UNCHANGED vs R3/R9
// (g+1, vmcnt(3)) => HBM traffic should stay ~287 MB (R7's +180 MB came
// from depth-2, this isolates that). Ps keeps the verified [64][132]
// layout, hosted in the FREE buffer's 24 KB (As+Bs contiguous; 16.9 KB fits).
// Register budget unchanged (one SGPR rotation index): 64 VGPR + 64 AGPR.
// LDS: 3 x 24576 (buf k at k*24576: As 8 KB, Bs 16 KB) + Zacc/invZ = 74 KB
// -> still 2 blocks/CU (80 KB limit). Obuf [64][129] f32 @ 0 (epilogue).
// ---------------------------------------------------------------------------
#define BUFSZ   24576
#define ZA_OFF  73728
#define IZ_OFF  73984
#define SMEM_BYTES 74240

// Stage chunk g (k0 = (g&7)*64, t0 = (g>>3)*128): As 1 issue + Bs 2 issues,
// 16B/lane. Source address carries the XOR swizzle (byte ^= (row&7)<<4) so
// LDS stays linear (global_load_lds requirement) and the swizzled
// ds_read_b128 on the consume side is bank-conflict-spread (rule #21: the
// source permutation and the read permutation are the same involution).
__device__ __forceinline__ void issue_tiles(const char* __restrict__ Qn,
                                            const char* __restrict__ Kn,
                                            char* as_lds, char* bs_lds,
                                            int g, int tid) {
  if (g > 63) g = 63;                       // clamped re-issue (harmless dup)
  const int k0b = (g & 7) * (BK * 2);
  const int t0  = (g >> 3) * TBLK;
  {
    const int row  = tid >> 3;              // c row 0..63
    const int colb = ((tid & 7) << 4) ^ ((row & 7) << 4);
    gload_lds16(Qn + (size_t)row * (DDIM * 2) + k0b + colb, as_lds + tid * 16);
  }
  #pragma unroll
  for (int i = 0; i < 2; ++i) {
    const int idx  = i * 512 + tid;
    const int row  = idx >> 3;              // t row 0..127
    const int colb = ((idx & 7) << 4) ^ ((row & 7) << 4);
    gload_lds16(Kn + (size_t)(t0 + row) * (DDIM * 2) + k0b + colb, bs_lds + idx * 16);
  }
}

__global__ __launch_bounds__(512, 4)   // 2 blocks/CU; 128-reg unified budget
void attn_main(const unsigned short* __restrict__ Qt,   // [n][c][d] bf16
               const unsigned short* __restrict__ Kt,   // [n][t][d] bf16
               const unsigned short* __restrict__ Vb,   // [n][d][t] bf16
               const float* __restrict__ ratios,
               float* __restrict__ out)
{
  __shared__ __align__(16) char smem[SMEM_BYTES];
  float* Zacc = (float*)(smem + ZA_OFF);
  float* invZ = (float*)(smem + IZ_OFF);
  float* Obuf = (float*)smem;

  // XCD swizzle: all 8 c-blocks of one sample -> same XCD (same L2)
  const int lin = blockIdx.x + (int)gridDim.x * blockIdx.y;  // 0..511
  const int n   = 8 * (lin & 7) + (lin >> 6);
  const int c0  = ((lin >> 3) & 7) * CB;

  const int tid  = threadIdx.x;
  const int wave = tid >> 6;
  const int lane = tid & 63;
  const int l31  = lane & 31;
  const int lhi  = lane >> 5;

  float r = ratios[n];
  int vw = (int)floorf(128.0f * r + 0.5f);
  if (vw > 128) vw = 128;

  const char* Qn = (const char*)(Qt + (size_t)n * CDIM * DDIM + (size_t)c0 * DDIM);
  const char* Kn = (const char*)(Kt + (size_t)n * TDIM * DDIM);
  const unsigned short* Vn = Vb + (size_t)n * DDIM * TDIM;

  f32x16 o_acc[2][2];
  #pragma unroll
  for (int a = 0; a < 2; ++a)
    #pragma unroll
    for (int b = 0; b < 2; ++b)
      #pragma unroll
      for (int i = 0; i < 16; ++i) o_acc[a][b][i] = 0.0f;

  const int p1_ct = wave & 1;   // c strip (2 x 32)
  const int p1_tt = wave >> 1;  // t strip (4 x 32)

  if (tid < 64) Zacc[tid] = 0.0f;
  // prologue: chunk 0 -> buf0 only (kit0 issues chunk 1; vmcnt(3) then
  // leaves chunk 1's 3 loads in flight and guarantees chunk 0 landed)
  issue_tiles(Qn, Kn, smem, smem + 8192, 0, tid);
  // order Zacc init; do NOT drain vmcnt (prefetch stays in flight)
  LGKM_BARRIER();

  const int swz = (l31 & 7) << 4;
  const int aro = (32 * p1_ct + l31) * 128;
  const int bro = (32 * p1_tt + l31) * 128;

  int cur = 0;   // buffer (SGPR) holding the chunk computed this kit

  for (int tb = 0; tb < 8; ++tb) {
    const int t0 = tb * TBLK;
    f32x16 s_acc;
    #pragma unroll
    for (int i = 0; i < 16; ++i) s_acc[i] = 0.0f;

    // ---- phase 1: S(64x128) += Q^T K over d; tri-buf depth-1, 1 barrier/kit ----
    #pragma unroll
    for (int kit = 0; kit < 8; ++kit) {
      const int g = tb * 8 + kit;
      int nxt = cur + 1; if (nxt >= 3) nxt -= 3;
      char* curb = smem + cur * BUFSZ;
      char* nxtb = smem + nxt * BUFSZ;
      // prefetch chunk g+1 into the buffer consumed at kit g-2 (its reads
      // retired before the previous two barriers)
      issue_tiles(Qn, Kn, nxtb, nxtb + 8192, g + 1, tid);
      // wait for chunk g's 3 loads only (chunk g+1's 3 stay in flight)
      asm volatile("s_waitcnt vmcnt(3)\n\ts_barrier" ::: "memory");
      // no setprio: lockstep phase, T5-null regime (R9-verified)
      #pragma unroll
      for (int ks = 0; ks < 4; ++ks) {
        const int coff = (ks * 32 + 16 * lhi) ^ swz;
        s16x8 av = *(const s16x8*)(curb + aro + coff);
        s16x8 bv = *(const s16x8*)(curb + 8192 + bro + coff);
        s_acc = __builtin_amdgcn_mfma_f32_32x32x16_bf16(av, bv, s_acc, 0, 0, 0);
      }
      cur = nxt;
    }

    // free buffer: cur holds in-flight chunk (g+1); cur-1 was computed at
    // kit7; cur+1 was last read at kit6 (fully retired) -> hosts Ps (16.9 KB
    // in its 24 KB, verified [64][132] layout kept).
    int fb = cur + 1; if (fb >= 3) fb -= 3;
    unsigned short* Ps = (unsigned short*)(smem + fb * BUFSZ);

    // ---- phase 2: p = mask * exp(s*scale) ----
    {
      const int tcol = 32 * p1_tt + l31;
      const float pm = (tcol < vw) ? 1.0f : 0.0f;
      #pragma unroll
      for (int rg = 0; rg < 16; ++rg) {
        const int c_loc = 32 * p1_ct + (rg & 3) + 8 * (rg >> 2) + 4 * lhi;
        float p = pm * __expf(s_acc[rg] * SCALE);
        Ps[c_loc * 132 + tcol] = f2bf(p);
      }
    }
    LGKM_BARRIER();

    // ---- Z row-sum accumulation (vectorized b64 reads) ----
    {
      const int zr = tid >> 3;
      const int zo = (tid & 7) * 16;
      float zs = 0.0f;
      #pragma unroll
      for (int j4 = 0; j4 < 4; ++j4) {
        s16x4 v4 = *(const s16x4*)&Ps[zr * 132 + zo + 4 * j4];
        zs += bf2f((unsigned short)v4[0]) + bf2f((unsigned short)v4[1])
            + bf2f((unsigned short)v4[2]) + bf2f((unsigned short)v4[3]);
      }
      zs += __shfl_xor(zs, 1);
      zs += __shfl_xor(zs, 2);
      zs += __shfl_xor(zs, 4);
      if ((tid & 7) == 0) Zacc[zr] += zs;
    }

    // ---- phase 3: O += P * V^T ; V direct bf16 from global, dist-2 prefetch ----
    {
      const unsigned short* vr0 = Vn + (size_t)(64 * wave + l31) * TDIM + t0;
      const unsigned short* vr1 = vr0 + (size_t)32 * TDIM;
      s16x8 va[2], vb2[2];
      va[0]  = *(const s16x8*)(vr0 + 8 * lhi);
      vb2[0] = *(const s16x8*)(vr1 + 8 * lhi);
      va[1]  = *(const s16x8*)(vr0 + 16 + 8 * lhi);
      vb2[1] = *(const s16x8*)(vr1 + 16 + 8 * lhi);
      #pragma unroll
      for (int ks = 0; ks < 8; ++ks) {
        const int kk = ks * 16 + 8 * lhi;
        s16x8 pa[2];
        #pragma unroll
        for (int ci = 0; ci < 2; ++ci) {
          const int rowb = (32 * ci + l31) * 132;
          s16x4 x0 = *(const s16x4*)&Ps[rowb + kk];
          s16x4 x1 = *(const s16x4*)&Ps[rowb + kk + 4];
          pa[ci] = __builtin_shufflevector(x0, x1, 0, 1, 2, 3, 4, 5, 6, 7);
        }
        s16x8 b0 = va[ks & 1];
        s16x8 b1 = vb2[ks & 1];
        if (ks < 6) {
          va[ks & 1]  = *(const s16x8*)(vr0 + (ks + 2) * 16 + 8 * lhi);
          vb2[ks & 1] = *(const s16x8*)(vr1 + (ks + 2) * 16 + 8 * lhi);
        }
        __builtin_amdgcn_s_setprio(1);     // T5 kept: wave-independent phase
        o_acc[0][0] = __builtin_amdgcn_mfma_f32_32x32x16_bf16(pa[0], b0, o_acc[0][0], 0, 0, 0);
        o_acc[1][0] = __builtin_amdgcn_mfma_f32_32x32x16_bf16(pa[1], b0, o_acc[1][0], 0, 0, 0);
        o_acc[0][1] = __builtin_amdgcn_mfma_f32_32x32x16_bf16(pa[0], b1, o_acc[0][1], 0, 0, 0);
        o_acc[1][1] = __builtin_amdgcn_mfma_f32_32x32x16_bf16(pa[1], b1, o_acc[1][1], 0, 0, 0);
        __builtin_amdgcn_s_setprio(0);
      }
    }

    // tb-end barrier: all waves' Ps reads done before next tb's kit0 issues
    // DMA into fb (= Ps host). lgkm-only: in-flight vmem stays.
    LGKM_BARRIER();
  }

  // ---- epilogue: drain the clamped trailing prefetch, then normalize+store ----
  asm volatile("s_waitcnt vmcnt(0) lgkmcnt(0)\n\ts_barrier" ::: "memory");
  if (tid < 64) invZ[tid] = 1.0f / Zacc[tid];
  LGKM_BARRIER();

  float* outn = out + (size_t)n * DDIM * CDIM + c0;
  for (int ch = 0; ch < 4; ++ch) {          // d-chunk of 128
    if ((wave >> 1) == ch) {
      const int s = wave & 1;
      #pragma unroll
      for (int ci = 0; ci < 2; ++ci)
        #pragma unroll
        for (int dt = 0; dt < 2; ++dt)
          #pragma unroll
          for (int rg = 0; rg < 16; ++rg) {
            const int c_loc = 32 * ci + (rg & 3) + 8 * (rg >> 2) + 4 * lhi;
            const int ddl = 64 * s + 32 * dt + l31;
            Obuf[c_loc * 129 + ddl] = o_acc[ci][dt][rg] * invZ[c_loc];
          }
    }
    LGKM_BARRIER();
    {
      const int c  = tid & 63;
      const int db = tid >> 6;
      #pragma unroll
      for (int p = 0; p < 16; ++p) {
        const int ddl = db + 8 * p;
        outn[(size_t)(128 * ch + ddl) * CDIM + c] = Obuf[c * 129 + ddl];
      }
    }
    LGKM_BARRIER();
  }
}

// ===========================================================================
// FALLBACK PATH — previous session's harness-verified kernel (545.3 µs),
// used only if ws_size is too small for the workspace path.
// ===========================================================================
#define FB_AS_OFF 0
#define FB_BS_OFF 8704
#define FB_PS_OFF 26112
#define FB_ZA_OFF 43008
#define FB_IZ_OFF 43264
#define FB_SMEM_BYTES 43520

struct QKRegs { f32x4 q0, q1, ka0, ka1, kb0, kb1; };
struct VRegs  { f32x4 a0, a1, b0, b1; };

__device__ __forceinline__ void issue_qk(QKRegs& r,
                                         const float* __restrict__ qbase,
                                         const float* __restrict__ kbase,
                                         int k0, int t0,
                                         int a_mg, int a_kq, int b_tg, int b_kq) {
  const float* gq = qbase + (size_t)(k0 + 2 * a_kq) * CDIM + 4 * a_mg;
  r.q0 = *(const f32x4*)gq;
  r.q1 = *(const f32x4*)(gq + CDIM);
  const float* gk0 = kbase + (size_t)(k0 + 2 * b_kq) * TDIM + t0 + 4 * b_tg;
  const float* gk1 = gk0 + (size_t)32 * TDIM;
  r.ka0 = *(const f32x4*)gk0;
  r.ka1 = *(const f32x4*)(gk0 + TDIM);
  r.kb0 = *(const f32x4*)gk1;
  r.kb1 = *(const f32x4*)(gk1 + TDIM);
}

__device__ __forceinline__ void issue_v(VRegs& r,
                                        const float* __restrict__ vrow0,
                                        int ks, int lhi) {
  const int kk = ks * 16 + 8 * lhi;
  const float* vp0 = vrow0 + kk;
  r.a0 = *(const f32x4*)vp0;
  r.a1 = *(const f32x4*)(vp0 + 4);
  const float* vp1 = vp0 + (size_t)32 * TDIM;
  r.b0 = *(const f32x4*)vp1;
  r.b1 = *(const f32x4*)(vp1 + 4);
}

__device__ __forceinline__ s16x8 cvt_bv(const f32x4& x0, const f32x4& x1) {
  s16x8 bv;
  bv[0] = (short)f2bf(x0[0]); bv[1] = (short)f2bf(x0[1]);
  bv[2] = (short)f2bf(x0[2]); bv[3] = (short)f2bf(x0[3]);
  bv[4] = (short)f2bf(x1[0]); bv[5] = (short)f2bf(x1[1]);
  bv[6] = (short)f2bf(x1[2]); bv[7] = (short)f2bf(x1[3]);
  return bv;
}

__global__ __launch_bounds__(512, 1)
void attn_fused_fallback(const float* __restrict__ query,
                         const float* __restrict__ key,
                         const float* __restrict__ value,
                         const float* __restrict__ ratios,
                         float* __restrict__ out)
{
  __shared__ __align__(16) char smem[FB_SMEM_BYTES];
  unsigned short* As = (unsigned short*)(smem + FB_AS_OFF);
  unsigned short* Bs = (unsigned short*)(smem + FB_BS_OFF);
  unsigned short* Ps = (unsigned short*)(smem + FB_PS_OFF);
  float* Zacc = (float*)(smem + FB_ZA_OFF);
  float* invZ = (float*)(smem + FB_IZ_OFF);
  float* Obuf = (float*)(smem + FB_AS_OFF);

  const int lin  = blockIdx.x + (int)gridDim.x * blockIdx.y;  // 0..511
  const int n    = 8 * (lin & 7) + (lin >> 6);
  const int c0   = ((lin >> 3) & 7) * CB;

  const int tid  = threadIdx.x;
  const int wave = tid >> 6;
  const int lane = tid & 63;
  const int l31  = lane & 31;
  const int lhi  = lane >> 5;

  float r = ratios[n];
  int vw = (int)floorf(128.0f * r + 0.5f);
  if (vw > 128) vw = 128;

  if (tid < 64) Zacc[tid] = 0.0f;

  const float* qbase = query + (size_t)n * DDIM * CDIM + c0;
  const float* kbase = key   + (size_t)n * DDIM * TDIM;
  const float* vbase = value + (size_t)n * DDIM * TDIM;

  f32x16 o_acc[2][2];
  #pragma unroll
  for (int a = 0; a < 2; ++a)
    #pragma unroll
    for (int b = 0; b < 2; ++b)
      #pragma unroll
      for (int i = 0; i < 16; ++i) o_acc[a][b][i] = 0.0f;

  const int p1_ct = wave & 1;
  const int p1_tt = wave >> 1;
  const int a_mg = tid & 15, a_kq = tid >> 4;
  const int b_tg = tid & 31, b_kq = tid >> 5;
  const float* vrow0_base = vbase + (size_t)(64 * wave + l31) * TDIM;

  QKRegs buf[2];
  issue_qk(buf[0], qbase, kbase, 0,  0, a_mg, a_kq, b_tg, b_kq);
  issue_qk(buf[1], qbase, kbase, BK, 0, a_mg, a_kq, b_tg, b_kq);

  LGKM_BARRIER();

  for (int tb = 0; tb < 8; ++tb) {
    const int t0 = tb * TBLK;
    f32x16 s_acc;
    #pragma unroll
    for (int i = 0; i < 16; ++i) s_acc[i] = 0.0f;

    #pragma unroll
    for (int kit = 0; kit < 8; ++kit) {
      const int g = tb * 8 + kit;
      QKRegs& rb = buf[kit & 1];

      LGKM_BARRIER();

      #pragma unroll
      for (int j = 0; j < 4; ++j) {
        unsigned int pk = (unsigned int)f2bf(rb.q0[j]) | ((unsigned int)f2bf(rb.q1[j]) << 16);
        *(unsigned int*)&As[(4 * a_mg + j) * 68 + 2 * a_kq] = pk;
      }
      #pragma unroll
      for (int j = 0; j < 4; ++j) {
        unsigned int p0 = (unsigned int)f2bf(rb.ka0[j]) | ((unsigned int)f2bf(rb.ka1[j]) << 16);
        unsigned int p1 = (unsigned int)f2bf(rb.kb0[j]) | ((unsigned int)f2bf(rb.kb1[j]) << 16);
        *(unsigned int*)&Bs[(4 * b_tg + j) * 68 + 2 * b_kq]      = p0;
        *(unsigned int*)&Bs[(4 * b_tg + j) * 68 + 2 * b_kq + 32] = p1;
      }

      {
        int gg = g + 2; if (gg > 63) gg = 63;
        issue_qk(rb, qbase, kbase, (gg & 7) * BK, (gg >> 3) * TBLK,
                 a_mg, a_kq, b_tg, b_kq);
      }

      LGKM_BARRIER();

      const int arow = (32 * p1_ct + l31) * 68;
      const int brow = (32 * p1_tt + l31) * 68;
      #pragma unroll
      for (int ks = 0; ks < 4; ++ks) {
        const int koff = ks * 16 + 8 * lhi;
        s16x4 a0 = *(const s16x4*)&As[arow + koff];
        s16x4 a1 = *(const s16x4*)&As[arow + koff + 4];
        s16x4 b0 = *(const s16x4*)&Bs[brow + koff];
        s16x4 b1 = *(const s16x4*)&Bs[brow + koff + 4];
        s16x8 av = __builtin_shufflevector(a0, a1, 0, 1, 2, 3, 4, 5, 6, 7);
        s16x8 bv = __builtin_shufflevector(b0, b1, 0, 1, 2, 3, 4, 5, 6, 7);
        s_acc = __builtin_amdgcn_mfma_f32_32x32x16_bf16(av, bv, s_acc, 0, 0, 0);
      }
    }

    {
      const int tcol = 32 * p1_tt + l31;
      const float pm = (tcol < vw) ? 1.0f : 0.0f;
      #pragma unroll
      for (int rg = 0; rg < 16; ++rg) {
        const int c_loc = 32 * p1_ct + (rg & 3) + 8 * (rg >> 2) + 4 * lhi;
        float p = pm * __expf(s_acc[rg] * SCALE);
        Ps[c_loc * 132 + tcol] = f2bf(p);
      }
    }
    LGKM_BARRIER();

    {
      const int zr = tid >> 3;
      const int zo = (tid & 7) * 16;
      float zs = 0.0f;
      #pragma unroll
      for (int j = 0; j < 16; ++j) zs += bf2f(Ps[zr * 132 + zo + j]);
      zs += __shfl_xor(zs, 1);
      zs += __shfl_xor(zs, 2);
      zs += __shfl_xor(zs, 4);
      if ((tid & 7) == 0) Zacc[zr] += zs;
    }

    {
      const float* vrow0 = vrow0_base + t0;
      VRegs vb[2];
      issue_v(vb[0], vrow0, 0, lhi);
      issue_v(vb[1], vrow0, 1, lhi);
      #pragma unroll
      for (int ks = 0; ks < 8; ++ks) {
        const int kk = ks * 16 + 8 * lhi;
        s16x8 pa[2];
        #pragma unroll
        for (int ci = 0; ci < 2; ++ci) {
          const int row = (32 * ci + l31) * 132;
          s16x4 x0 = *(const s16x4*)&Ps[row + kk];
          s16x4 x1 = *(const s16x4*)&Ps[row + kk + 4];
          pa[ci] = __builtin_shufflevector(x0, x1, 0, 1, 2, 3, 4, 5, 6, 7);
        }
        VRegs& vr = vb[ks & 1];
        s16x8 bv0 = cvt_bv(vr.a0, vr.a1);
        s16x8 bv1 = cvt_bv(vr.b0, vr.b1);
        if (ks < 6) issue_v(vr, vrow0, ks + 2, lhi);
        o_acc[0][0] = __builtin_amdgcn_mfma_f32_32x32x16_bf16(pa[0], bv0, o_acc[0][0], 0, 0, 0);
        o_acc[1][0] = __builtin_amdgcn_mfma_f32_32x32x16_bf16(pa[1], bv0, o_acc[1][0], 0, 0, 0);
        o_acc[0][1] = __builtin_amdgcn_mfma_f32_32x32x16_bf16(pa[0], bv1, o_acc[0][1], 0, 0, 0);
        o_acc[1][1] = __builtin_amdgcn_mfma_f32_32x32x16_bf16(pa[1], bv1, o_acc[1][1], 0, 0, 0);
      }
    }
  }

  LGKM_BARRIER();
  if (tid < 64) invZ[tid] = 1.0f / Zacc[tid];
  LGKM_BARRIER();

  float* outn = out + (size_t)n * DDIM * CDIM + c0;
  for (int ch = 0; ch < 4; ++ch) {
    if ((wave >> 1) == ch) {
      const int s = wave & 1;
      #pragma unroll
      for (int ci = 0; ci < 2; ++ci)
        #pragma unroll
        for (int dt = 0; dt < 2; ++dt)
          #pragma unroll
          for (int rg = 0; rg < 16; ++rg) {
            const int c_loc = 32 * ci + (rg & 3) + 8 * (rg >> 2) + 4 * lhi;
            const int ddl = 64 * s + 32 * dt + l31;
            Obuf[c_loc * 129 + ddl] = o_acc[ci][dt][rg] * invZ[c_loc];
          }
    }
    LGKM_BARRIER();
    {
      const int c = tid & 63;
      const int db = tid >> 6;
      #pragma unroll
      for (int p = 0; p < 16; ++p) {
        const int ddl = db + 8 * p;
        outn[(size_t)(128 * ch + ddl) * CDIM + c] = Obuf[c * 129 + ddl];
      }
    }
    LGKM_BARRIER();
  }
}

extern "C" void kernel_launch(void* const* d_in, const int* in_sizes, int n_in,
                              void* d_out, int out_size, void* d_ws, size_t ws_size,
                              hipStream_t stream) {
  const float* query  = (const float*)d_in[0];
  const float* key    = (const float*)d_in[1];
  const float* value  = (const float*)d_in[2];
  const float* ratios = (const float*)d_in[3];
  float* out = (float*)d_out;
  (void)in_sizes; (void)n_in; (void)out_size;

  // workspace: Qt (32 MB) | Kt (64 MB) | Vb (64 MB)  => 160 MB bf16 total
  const size_t needQ = (size_t)NS * CDIM * DDIM;       // shorts
  const size_t needK = (size_t)NS * TDIM * DDIM;       // shorts
  const size_t needV = (size_t)NS * DDIM * TDIM;       // shorts
  const size_t need_bytes = (needQ + needK + needV) * sizeof(unsigned short);

  if (d_ws != nullptr && ws_size >= need_bytes) {
    unsigned short* Qt = (unsigned short*)d_ws;
    unsigned short* Kt = Qt + needQ;
    unsigned short* Vb = Kt + needK;
    prep_kernel<<<dim3(14336), 256, 0, stream>>>(query, key, value, Qt, Kt, Vb);
    attn_main<<<dim3(CDIM / CB, NS), 512, 0, stream>>>(Qt, Kt, Vb, ratios, out);
  } else {
    attn_fused_fallback<<<dim3(CDIM / CB, NS), 512, 0, stream>>>(query, key, value, ratios, out);
  }
}